// Round 3
// baseline (2211.694 us; speedup 1.0000x reference)
//
#include <hip/hip_runtime.h>
#include <hip/hip_bf16.h>

// ---------------------------------------------------------------------------
// Problem constants (reference: B,N,T,P,H = 256,101,128,4,16)
// ---------------------------------------------------------------------------
constexpr int B = 256;
constexpr int N = 101;
constexpr int T = 128;

typedef float vf2 __attribute__((ext_vector_type(2)));
typedef short s8v __attribute__((ext_vector_type(8)));    // 8 bf16 (4 VGPRs)
typedef unsigned short u8v __attribute__((ext_vector_type(8)));
typedef float f4v __attribute__((ext_vector_type(4)));    // MFMA accum

__device__ __forceinline__ float frcp(float x) { return __builtin_amdgcn_rcpf(x); }
__device__ __forceinline__ float sigmoidf_(float x) { return frcp(1.f + __expf(-x)); }
__device__ __forceinline__ float tanhf_(float x) { return 2.f * frcp(1.f + __expf(-2.f * x)) - 1.f; }

// fp32 -> bf16 bits, round-nearest-even
__device__ __forceinline__ unsigned short f2bf(float x) {
  unsigned int u = __float_as_uint(x);
  u = (u + 0x7FFFu + ((u >> 16) & 1u)) >> 16;
  return (unsigned short)u;
}

// XCD-aware n-swizzle (R7: cut cc FETCH 605->140 MB). Bijection on [0,101).
__device__ __forceinline__ int swz_n(int L) {
  int q = L & 7, r = L >> 3;
  return q * 13 - (q > 5 ? (q - 5) : 0) + r;
}

// ---------------------------------------------------------------------------
// K1: LSTM. EXACT R0 structure (best measured: 221 us) with the single
// validated change: proj folded into input weights (wf = W_ih@pw,
// bias += W_ih@pb) - deletes the per-step x-proj (16 pk-FMA/lane-step).
// 8 seqs/wave (sub=lane>>4 owns a vf2 seq-pair), h via per-sub LDS row,
// two barriers per step, x loaded from global in-loop (L2/L3-hot).
// ---------------------------------------------------------------------------
__global__ __launch_bounds__(64) void lstm_kernel(
    const float* __restrict__ x, const float* __restrict__ pw,
    const float* __restrict__ pb, const float* __restrict__ w_ih,
    const float* __restrict__ w_hh, const float* __restrict__ b_ih,
    const float* __restrict__ b_hh, float* __restrict__ h_out) {
  __shared__ vf2 sh[4][16];  // [sub][unit] -> (rowA, rowB)
  const int lane = threadIdx.x;
  const int sub = lane >> 4;
  const int k = lane & 15;
  const int row = blockIdx.x * 8 + sub * 2;  // 3232*8 = 25856

  float wf[4][4], whh[4][16], bias[4];
#pragma unroll
  for (int q = 0; q < 4; q++) {
    const int j = q * 16 + k;  // gate order i,f,g,o
    float bp = b_ih[j] + b_hh[j];
#pragma unroll
    for (int c = 0; c < 4; c++) bp += w_ih[j * 4 + c] * pb[c];
    bias[q] = bp;
#pragma unroll
    for (int p = 0; p < 4; p++) {
      float s = 0.f;
#pragma unroll
      for (int c = 0; c < 4; c++) s += w_ih[j * 4 + c] * pw[c * 4 + p];
      wf[q][p] = s;
    }
#pragma unroll
    for (int m = 0; m < 16; m++) whh[q][m] = w_hh[j * 16 + m];
  }

  vf2 h = {0.f, 0.f}, c = {0.f, 0.f};
  sh[sub][k] = h;
  const float4* xpA = (const float4*)x + (size_t)row * T;
  const float4* xpB = xpA + T;

#pragma unroll 1
  for (int t = 0; t < T; t++) {
    __syncthreads();
    float4 xa = xpA[t];
    float4 xb = xpB[t];
    vf2 xc0 = {xa.x, xb.x}, xc1 = {xa.y, xb.y};
    vf2 xc2 = {xa.z, xb.z}, xc3 = {xa.w, xb.w};
    vf2 a0 = {bias[0], bias[0]}, a1 = {bias[1], bias[1]};
    vf2 a2 = {bias[2], bias[2]}, a3 = {bias[3], bias[3]};
    a0 += wf[0][0] * xc0 + wf[0][1] * xc1 + wf[0][2] * xc2 + wf[0][3] * xc3;
    a1 += wf[1][0] * xc0 + wf[1][1] * xc1 + wf[1][2] * xc2 + wf[1][3] * xc3;
    a2 += wf[2][0] * xc0 + wf[2][1] * xc1 + wf[2][2] * xc2 + wf[2][3] * xc3;
    a3 += wf[3][0] * xc0 + wf[3][1] * xc1 + wf[3][2] * xc2 + wf[3][3] * xc3;
#pragma unroll
    for (int mm = 0; mm < 4; mm++) {
      vf2 hm0 = sh[sub][mm * 4 + 0];
      vf2 hm1 = sh[sub][mm * 4 + 1];
      vf2 hm2 = sh[sub][mm * 4 + 2];
      vf2 hm3 = sh[sub][mm * 4 + 3];
      a0 += whh[0][mm * 4 + 0] * hm0 + whh[0][mm * 4 + 1] * hm1 +
            whh[0][mm * 4 + 2] * hm2 + whh[0][mm * 4 + 3] * hm3;
      a1 += whh[1][mm * 4 + 0] * hm0 + whh[1][mm * 4 + 1] * hm1 +
            whh[1][mm * 4 + 2] * hm2 + whh[1][mm * 4 + 3] * hm3;
      a2 += whh[2][mm * 4 + 0] * hm0 + whh[2][mm * 4 + 1] * hm1 +
            whh[2][mm * 4 + 2] * hm2 + whh[2][mm * 4 + 3] * hm3;
      a3 += whh[3][mm * 4 + 0] * hm0 + whh[3][mm * 4 + 1] * hm1 +
            whh[3][mm * 4 + 2] * hm2 + whh[3][mm * 4 + 3] * hm3;
    }
    vf2 ig, fg, gg, og, tc;
    ig.x = sigmoidf_(a0.x); ig.y = sigmoidf_(a0.y);
    fg.x = sigmoidf_(a1.x); fg.y = sigmoidf_(a1.y);
    gg.x = tanhf_(a2.x);    gg.y = tanhf_(a2.y);
    og.x = sigmoidf_(a3.x); og.y = sigmoidf_(a3.y);
    c = fg * c + ig * gg;
    tc.x = tanhf_(c.x);     tc.y = tanhf_(c.y);
    h = og * tc;
    __syncthreads();
    sh[sub][k] = h;
  }
  h_out[(size_t)row * 16 + k] = h.x;
  h_out[(size_t)(row + 1) * 16 + k] = h.y;
}

// ---------------------------------------------------------------------------
// Prep: pack cc conv weights into MFMA A-fragment order (bf16). Unchanged.
// ---------------------------------------------------------------------------
__global__ void prep_kernel(const float* __restrict__ t1c,
                            const float* __restrict__ t2c,
                            const float* __restrict__ t3c,
                            unsigned short* __restrict__ apk) {
  const int L = threadIdx.x;  // 64 threads
  const int co = L & 15, q = L >> 4;
#pragma unroll 1
  for (int set = 0; set < 15; set++) {
    int s, p;
    if (set < 3) { s = 0; p = set; }
    else if (set < 9) { s = 1; p = set - 3; }
    else { s = 2; p = set - 9; }
    u8v f;
#pragma unroll
    for (int j = 0; j < 8; j++) {
      float val = 0.f;
      if (s == 0) {
        int dn = p * 4 + q, ci = j;
        if (co < 8 && dn < 11) val = t1c[(co * 8 + ci) * 11 + dn];
      } else {
        int dn = p * 2 + (q >> 1), ci = (q & 1) * 8 + j;
        const float* w = (s == 1) ? t2c : t3c;
        if (dn < 11) val = w[(co * 16 + ci) * 11 + dn];
      }
      f[j] = f2bf(val);
    }
    *(u8v*)&apk[(set * 64 + L) * 8] = f;
  }
}

// ---------------------------------------------------------------------------
// K2 (stage 1 only): fused d1+d2, proj folded, fp32 x input, bf16
// channel-interleaved output [by][n][t][8]. R5-proven scalar streaming.
// ---------------------------------------------------------------------------
__global__ __launch_bounds__(128) void d12a_kernel(
    const float* __restrict__ xin,
    const float* __restrict__ pw, const float* __restrict__ pb,
    const float* __restrict__ w1,  // [8][4][3]
    const float* __restrict__ w2,  // [8][8][3]
    unsigned short* __restrict__ out, int b0) {
  constexpr int CI = 4, CO = 8, DIL = 1;
  const int t = threadIdx.x;
  const int n = swz_n(blockIdx.x), by = blockIdx.y;
  const int b = b0 + by;

  float r1[3][CO];
#pragma unroll
  for (int u = 0; u < 3; u++)
#pragma unroll
    for (int co = 0; co < CO; co++) r1[u][co] = 0.f;

  const float4* xp = (const float4*)xin + ((size_t)b * N + n) * T;
  float px[5][4];
#pragma unroll
  for (int v = 0; v < 5; v++) {
    int idx = t - v * DIL;
    float4 xr = xp[idx < 0 ? 0 : idx];
    bool ok = idx >= 0;
    px[v][0] = ok ? pb[0] + pw[0] * xr.x + pw[1] * xr.y + pw[2] * xr.z + pw[3] * xr.w : 0.f;
    px[v][1] = ok ? pb[1] + pw[4] * xr.x + pw[5] * xr.y + pw[6] * xr.z + pw[7] * xr.w : 0.f;
    px[v][2] = ok ? pb[2] + pw[8] * xr.x + pw[9] * xr.y + pw[10] * xr.z + pw[11] * xr.w : 0.f;
    px[v][3] = ok ? pb[3] + pw[12] * xr.x + pw[13] * xr.y + pw[14] * xr.z + pw[15] * xr.w : 0.f;
  }
#pragma unroll
  for (int ci = 0; ci < CI; ci++) {
#pragma unroll
    for (int j = 0; j < 3; j++) {
#pragma unroll
      for (int co = 0; co < CO; co++) {
        float w = w1[(co * CI + ci) * 3 + j];
#pragma unroll
        for (int u = 0; u < 3; u++) r1[u][co] += w * px[u + 2 - j][ci];
      }
    }
  }
#pragma unroll
  for (int u = 0; u < 3; u++)
#pragma unroll
    for (int co = 0; co < CO; co++) r1[u][co] = fmaxf(r1[u][co], 0.f);

  float acc[CO];
#pragma unroll
  for (int co = 0; co < CO; co++) acc[co] = 0.f;
#pragma unroll
  for (int cm = 0; cm < CO; cm++) {
#pragma unroll
    for (int j = 0; j < 3; j++) {
#pragma unroll
      for (int co = 0; co < CO; co++)
        acc[co] += w2[(co * CO + cm) * 3 + j] * r1[2 - j][cm];
    }
  }
  unsigned short* op = &out[(((size_t)by * N + n) * T + t) * CO];
  u8v a;
#pragma unroll
  for (int j = 0; j < 8; j++) a[j] = f2bf(fmaxf(acc[j], 0.f));
  *(u8v*)&op[0] = a;
}

// ---------------------------------------------------------------------------
// K4/K6 (stages 2/3) REWRITE (d12s): fused d1+d2 with d1 AMORTIZED via LDS.
// Old d12v recomputed each d1 tap 3x (2304 MAC/elem for d1 at stage 3);
// here each r1[cm][tau] is computed ONCE and shared across the block:
//   - 128 threads/block (2 waves, one t per thread) -> 6.3 waves/SIMD
//   - two cm-passes of 8 channels; LDS r1 buffer 8 x (T+HALO) fp32 (~4.3 KB)
//   - per-lane FMA: d1 768 + d2 768 (was 3072 pk at stage 3)
// r1(tau<0) = relu(conv of zero-padded x) = 0 exactly -> zeroed halo.
// fp32 throughout; output bf16 channel-interleaved [by][n][t][16].
// ---------------------------------------------------------------------------
template <int CI, int DIL>
__global__ __launch_bounds__(128) void d12s_kernel(
    const float* __restrict__ xin,   // [Bc][CI][N][T] fp32
    const float* __restrict__ w1,    // [16][CI][3]
    const float* __restrict__ w2,    // [16][16][3]
    unsigned short* __restrict__ out) {
  constexpr int CO = 16;
  constexpr int HALO = 2 * DIL;  // max back-reach of d2 taps
  __shared__ float r1s[8][T + HALO];

  const int t = threadIdx.x;  // 0..127
  const int n = swz_n(blockIdx.x), by = blockIdx.y;

  float acc[CO];
#pragma unroll
  for (int co = 0; co < CO; co++) acc[co] = 0.f;

#pragma unroll
  for (int pass = 0; pass < 2; pass++) {
    // WAR guard vs previous pass's d2 reads (no-op cost on first pass)
    __syncthreads();
    // zero the halo region (tau < 0 -> r1 = 0 exactly)
    if (t < 8 * HALO) {
      const int hr = t / HALO, hc = t % HALO;
      r1s[hr][hc] = 0.f;
    }
    // ---- d1: this pass's 8 cm channels at tau = t ----
    float r[8];
#pragma unroll
    for (int cm = 0; cm < 8; cm++) r[cm] = 0.f;
#pragma unroll
    for (int ci = 0; ci < CI; ci++) {
      const float* xp = xin + (((size_t)by * CI + ci) * N + n) * T;
      float xt[3];
#pragma unroll
      for (int j = 0; j < 3; j++) {
        int idx = t - DIL * j;
        xt[j] = (idx >= 0) ? xp[idx] : 0.f;
      }
#pragma unroll
      for (int cm = 0; cm < 8; cm++) {
#pragma unroll
        for (int j = 0; j < 3; j++)
          r[cm] += w1[((pass * 8 + cm) * CI + ci) * 3 + j] * xt[j];
      }
    }
#pragma unroll
    for (int cm = 0; cm < 8; cm++) r1s[cm][HALO + t] = fmaxf(r[cm], 0.f);
    __syncthreads();
    // ---- d2: accumulate this pass's cm contributions for all 16 co ----
#pragma unroll
    for (int cm = 0; cm < 8; cm++) {
      float rv[3];
#pragma unroll
      for (int j = 0; j < 3; j++) rv[j] = r1s[cm][HALO + t - DIL * j];
#pragma unroll
      for (int co = 0; co < CO; co++) {
#pragma unroll
        for (int j = 0; j < 3; j++)
          acc[co] += w2[(co * CO + pass * 8 + cm) * 3 + j] * rv[j];
      }
    }
  }

  unsigned short* op = &out[(((size_t)by * N + n) * T + t) * CO];
  u8v a0, a1;
#pragma unroll
  for (int j = 0; j < 8; j++) {
    a0[j] = f2bf(fmaxf(acc[j], 0.f));
    a1[j] = f2bf(fmaxf(acc[8 + j], 0.f));
  }
  *(u8v*)&op[0] = a0;
  *(u8v*)&op[8] = a1;
}

// ---------------------------------------------------------------------------
// K3/K5/K7: cross-stock 11x1 conv via MFMA (R10 version: fp32 out/residual).
// RESMODE: 0 = x-proj+rw (C=8), 1 = rw from fp32 H, 2 = identity fp32 H.
// ---------------------------------------------------------------------------
template <int C, int CIR, int RESMODE>
__global__ __launch_bounds__(64) void ccm_kernel(
    const unsigned short* __restrict__ zin,  // [Bc][N][T][C] bf16
    const unsigned short* __restrict__ apk,  // [NMF][64][8] bf16
    const float* __restrict__ resin,         // RESMODE 0: x; else fp32 planar
    const float* __restrict__ rw,
    const float* __restrict__ pw, const float* __restrict__ pb,
    float* __restrict__ out,                 // fp32 planar [Bc][C][N][T]
    int b0) {
  constexpr int NMF = (C == 8) ? 3 : 6;
  const int L = threadIdx.x;
  const int tcol = L & 15, q = L >> 4;
  const int n = swz_n(blockIdx.x);
  const int t = blockIdx.y * 16 + tcol;
  const int by = blockIdx.z;
  const int b = b0 + by;

  f4v d = {0.f, 0.f, 0.f, 0.f};
#pragma unroll
  for (int p = 0; p < NMF; p++) {
    int dn = (C == 8) ? (p * 4 + q) : (p * 2 + (q >> 1));
    int row = n + dn - 5;
    bool ok = (unsigned)row < (unsigned)N;
    int rowc = ok ? row : 0;
    const unsigned short* bp =
        &zin[(((size_t)by * N + rowc) * T + t) * C + ((C == 16) ? (q & 1) * 8 : 0)];
    s8v bfrag = *(const s8v*)bp;
    if (!ok) bfrag = (s8v){0, 0, 0, 0, 0, 0, 0, 0};
    s8v afrag = *(const s8v*)&apk[(p * 64 + L) * 8];
    d = __builtin_amdgcn_mfma_f32_16x16x32_bf16(afrag, bfrag, d, 0, 0, 0);
  }

  if (C == 8 && q >= 2) return;

  float y[4];
  if constexpr (RESMODE == 0) {
    float4 xr = ((const float4*)resin)[((size_t)b * N + n) * T + t];
    float xv[4];
#pragma unroll
    for (int j = 0; j < 4; j++)
      xv[j] = pb[j] + pw[j * 4 + 0] * xr.x + pw[j * 4 + 1] * xr.y +
              pw[j * 4 + 2] * xr.z + pw[j * 4 + 3] * xr.w;
#pragma unroll
    for (int r = 0; r < 4; r++) {
      int co = q * 4 + r;
      float rv = rw[co * 4 + 0] * xv[0] + rw[co * 4 + 1] * xv[1] +
                 rw[co * 4 + 2] * xv[2] + rw[co * 4 + 3] * xv[3];
      y[r] = fmaxf(rv + fmaxf(d[r], 0.f), 0.f);
    }
  } else if constexpr (RESMODE == 1) {
    float hv[CIR];
#pragma unroll
    for (int ci = 0; ci < CIR; ci++)
      hv[ci] = resin[(((size_t)by * CIR + ci) * N + n) * T + t];
#pragma unroll
    for (int r = 0; r < 4; r++) {
      int co = q * 4 + r;
      float rv = 0.f;
#pragma unroll
      for (int ci = 0; ci < CIR; ci++) rv += rw[co * CIR + ci] * hv[ci];
      y[r] = fmaxf(rv + fmaxf(d[r], 0.f), 0.f);
    }
  } else {
#pragma unroll
    for (int r = 0; r < 4; r++) {
      int co = q * 4 + r;
      float rv = resin[(((size_t)by * C + co) * N + n) * T + t];
      y[r] = fmaxf(rv + fmaxf(d[r], 0.f), 0.f);
    }
  }
#pragma unroll
  for (int r = 0; r < 4; r++) {
    int co = q * 4 + r;
    out[(((size_t)by * C + co) * N + n) * T + t] = y[r];
  }
}

// ---------------------------------------------------------------------------
// conv4: h4[b][o][n] = relu(sum_{ci,t} w4[o][ci][t] * Y[ci][t]).
// One 64-lane wave per (b,n); Y fp32 planar (R10 version).
// ---------------------------------------------------------------------------
__global__ __launch_bounds__(64) void conv4_kernel(
    const float* __restrict__ Y,   // [Bc][16][N][T]
    const float* __restrict__ w4,  // [16][16][T]
    float* __restrict__ h4,        // [B][16][N]
    int b0) {
  const int tl = threadIdx.x;
  const int n = swz_n(blockIdx.x), by = blockIdx.y;
  const int b = b0 + by;
  const int t0 = tl * 2;

  vf2 y[16];
#pragma unroll
  for (int ci = 0; ci < 16; ci++)
    y[ci] = *(const vf2*)&Y[(((size_t)by * 16 + ci) * N + n) * T + t0];

#pragma unroll 1
  for (int o = 0; o < 16; o++) {
    vf2 s = (vf2)0.f;
#pragma unroll
    for (int ci = 0; ci < 16; ci++) {
      vf2 w = *(const vf2*)&w4[(size_t)(o * 16 + ci) * T + t0];
      s += w * y[ci];
    }
    float sum = s.x + s.y;
    sum += __shfl_down(sum, 32);
    sum += __shfl_down(sum, 16);
    sum += __shfl_down(sum, 8);
    sum += __shfl_down(sum, 4);
    sum += __shfl_down(sum, 2);
    sum += __shfl_down(sum, 1);
    if (tl == 0) h4[((size_t)b * 16 + o) * N + n] = fmaxf(sum, 0.f);
  }
}

// ---------------------------------------------------------------------------
// K8: logits (torch reshape scramble) + softmax over N
// ---------------------------------------------------------------------------
__global__ __launch_bounds__(128) void final_kernel(
    const float* __restrict__ hl, const float* __restrict__ h4,
    const float* __restrict__ ow, const float* __restrict__ ob,
    float* __restrict__ out) {
  __shared__ float red[128];
  int b = blockIdx.x, n = threadIdx.x;
  bool valid = n < N;
  float lv = 0.f;
  if (valid) {
    int idx = b * N + n;
    int sb = idx & (B - 1);
    int sn = idx >> 8;
    const float* h = &hl[((size_t)sb * N + sn) * 16];
    float a = ob[0];
#pragma unroll
    for (int k = 0; k < 16; k++) a += h[k] * ow[k];
#pragma unroll
    for (int c = 0; c < 16; c++) a += h4[((size_t)b * 16 + c) * N + n] * ow[16 + c];
    lv = a;
  }
  red[n] = valid ? lv : -1e30f;
  __syncthreads();
  for (int off = 64; off > 0; off >>= 1) {
    if (n < off) red[n] = fmaxf(red[n], red[n + off]);
    __syncthreads();
  }
  float m = red[0];
  __syncthreads();
  float e = valid ? __expf(lv - m) : 0.f;
  red[n] = e;
  __syncthreads();
  for (int off = 64; off > 0; off >>= 1) {
    if (n < off) red[n] += red[n + off];
    __syncthreads();
  }
  float s = red[0];
  if (valid) out[(size_t)b * N + n] = e / s;
}

// ---------------------------------------------------------------------------
// Launch. Chunked over B. Per-b unit: Zb1(bf16 8ch=4) + H1(fp32 8ch=8) +
// Zb2(bf16 16ch=8) + H2(fp32 16) + Y3(fp32 16) = 52 NT-floats.
// ---------------------------------------------------------------------------
extern "C" void kernel_launch(void* const* d_in, const int* in_sizes, int n_in,
                              void* d_out, int out_size, void* d_ws, size_t ws_size,
                              hipStream_t stream) {
  const float* x    = (const float*)d_in[0];
  const float* pw   = (const float*)d_in[1];
  const float* pb   = (const float*)d_in[2];
  const float* w_ih = (const float*)d_in[3];
  const float* w_hh = (const float*)d_in[4];
  const float* b_ih = (const float*)d_in[5];
  const float* b_hh = (const float*)d_in[6];
  const float* t1d1 = (const float*)d_in[7];
  const float* t1d2 = (const float*)d_in[8];
  const float* t1c  = (const float*)d_in[9];
  const float* t1r  = (const float*)d_in[10];
  const float* t2d1 = (const float*)d_in[11];
  const float* t2d2 = (const float*)d_in[12];
  const float* t2c  = (const float*)d_in[13];
  const float* t2r  = (const float*)d_in[14];
  const float* t3d1 = (const float*)d_in[15];
  const float* t3d2 = (const float*)d_in[16];
  const float* t3c  = (const float*)d_in[17];
  const float* w4   = (const float*)d_in[18];
  const float* ow   = (const float*)d_in[19];
  const float* ob   = (const float*)d_in[20];
  float* outp = (float*)d_out;

  const size_t NT = (size_t)N * T;            // 12928
  const size_t Bn16 = (size_t)B * N * 16;
  const size_t unit = 52 * NT;                // floats per chunked b
  const size_t fixed = 2 * Bn16 + 4096;       // hl + h4 + apk

  int Bc = 4;
  const int cands[7] = {256, 128, 64, 32, 16, 8, 4};
  for (int i = 0; i < 7; i++) {
    if ((cands[i] * unit + fixed) * sizeof(float) <= ws_size) { Bc = cands[i]; break; }
  }

  float* ws = (float*)d_ws;
  float* hl = ws;                              // [B*N][16]
  float* h4 = hl + Bn16;                       // [B][16][N]
  unsigned short* apk = (unsigned short*)(h4 + Bn16);  // 15*64*8 ushorts
  float* base = h4 + Bn16 + 4096;
  unsigned short* Zb1 = (unsigned short*)base;            // [Bc][N][T][8] bf16
  float* H1 = base + (size_t)Bc * 4 * NT;                 // [Bc][8][N][T]
  unsigned short* Zb2 = (unsigned short*)(H1 + (size_t)Bc * 8 * NT);  // [Bc][N][T][16]
  float* H2 = H1 + (size_t)Bc * 16 * NT;                  // [Bc][16][N][T]
  float* Y3 = H2 + (size_t)Bc * 16 * NT;                  // [Bc][16][N][T]

  prep_kernel<<<1, 64, 0, stream>>>(t1c, t2c, t3c, apk);
  lstm_kernel<<<(B * N) / 8, 64, 0, stream>>>(x, pw, pb, w_ih, w_hh, b_ih,
                                              b_hh, hl);

  dim3 g(N, Bc);
  dim3 gm(N, T / 16, Bc);
  for (int b0 = 0; b0 < B; b0 += Bc) {
    d12a_kernel<<<g, 128, 0, stream>>>(x, pw, pb, t1d1, t1d2, Zb1, b0);
    ccm_kernel<8, 4, 0><<<gm, 64, 0, stream>>>(
        Zb1, apk + 0 * 512, x, t1r, pw, pb, H1, b0);

    d12s_kernel<8, 2><<<g, 128, 0, stream>>>(H1, t2d1, t2d2, Zb2);
    ccm_kernel<16, 8, 1><<<gm, 64, 0, stream>>>(
        Zb2, apk + 3 * 512, H1, t2r, pw, pb, H2, b0);

    d12s_kernel<16, 4><<<g, 128, 0, stream>>>(H2, t3d1, t3d2, Zb2);
    ccm_kernel<16, 16, 2><<<gm, 64, 0, stream>>>(
        Zb2, apk + 9 * 512, H2, nullptr, pw, pb, Y3, b0);

    conv4_kernel<<<g, 64, 0, stream>>>(Y3, w4, h4, b0);
  }

  final_kernel<<<B, 128, 0, stream>>>(hl, h4, ow, ob, outp);
}

// Round 4
// 1096.974 us; speedup vs baseline: 2.0162x; 2.0162x over previous
//
#include <hip/hip_runtime.h>
#include <hip/hip_bf16.h>

// ---------------------------------------------------------------------------
// Problem constants (reference: B,N,T,P,H = 256,101,128,4,16)
// ---------------------------------------------------------------------------
constexpr int B = 256;
constexpr int N = 101;
constexpr int T = 128;

typedef float vf2 __attribute__((ext_vector_type(2)));
typedef short s8v __attribute__((ext_vector_type(8)));    // 8 bf16 (4 VGPRs)
typedef unsigned short u8v __attribute__((ext_vector_type(8)));
typedef unsigned short u4s __attribute__((ext_vector_type(4)));
typedef float f4v __attribute__((ext_vector_type(4)));    // MFMA accum

__device__ __forceinline__ float frcp(float x) { return __builtin_amdgcn_rcpf(x); }
__device__ __forceinline__ float sigmoidf_(float x) { return frcp(1.f + __expf(-x)); }
__device__ __forceinline__ float tanhf_(float x) { return 2.f * frcp(1.f + __expf(-2.f * x)) - 1.f; }

// fp32 -> bf16 bits, round-nearest-even
__device__ __forceinline__ unsigned short f2bf(float x) {
  unsigned int u = __float_as_uint(x);
  u = (u + 0x7FFFu + ((u >> 16) & 1u)) >> 16;
  return (unsigned short)u;
}

// XCD-aware n-swizzle (R7: cut cc FETCH 605->140 MB). Bijection on [0,101).
__device__ __forceinline__ int swz_n(int L) {
  int q = L & 7, r = L >> 3;
  return q * 13 - (q > 5 ? (q - 5) : 0) + r;
}

// ---------------------------------------------------------------------------
// K1: LSTM. R0 structure + proj fold (R3 version, measured <= ~218 us).
// 8 seqs/wave (sub=lane>>4 owns a vf2 seq-pair), h via per-sub LDS row.
// ---------------------------------------------------------------------------
__global__ __launch_bounds__(64) void lstm_kernel(
    const float* __restrict__ x, const float* __restrict__ pw,
    const float* __restrict__ pb, const float* __restrict__ w_ih,
    const float* __restrict__ w_hh, const float* __restrict__ b_ih,
    const float* __restrict__ b_hh, float* __restrict__ h_out) {
  __shared__ vf2 sh[4][16];  // [sub][unit] -> (rowA, rowB)
  const int lane = threadIdx.x;
  const int sub = lane >> 4;
  const int k = lane & 15;
  const int row = blockIdx.x * 8 + sub * 2;  // 3232*8 = 25856

  float wf[4][4], whh[4][16], bias[4];
#pragma unroll
  for (int q = 0; q < 4; q++) {
    const int j = q * 16 + k;  // gate order i,f,g,o
    float bp = b_ih[j] + b_hh[j];
#pragma unroll
    for (int c = 0; c < 4; c++) bp += w_ih[j * 4 + c] * pb[c];
    bias[q] = bp;
#pragma unroll
    for (int p = 0; p < 4; p++) {
      float s = 0.f;
#pragma unroll
      for (int c = 0; c < 4; c++) s += w_ih[j * 4 + c] * pw[c * 4 + p];
      wf[q][p] = s;
    }
#pragma unroll
    for (int m = 0; m < 16; m++) whh[q][m] = w_hh[j * 16 + m];
  }

  vf2 h = {0.f, 0.f}, c = {0.f, 0.f};
  sh[sub][k] = h;
  const float4* xpA = (const float4*)x + (size_t)row * T;
  const float4* xpB = xpA + T;

#pragma unroll 1
  for (int t = 0; t < T; t++) {
    __syncthreads();
    float4 xa = xpA[t];
    float4 xb = xpB[t];
    vf2 xc0 = {xa.x, xb.x}, xc1 = {xa.y, xb.y};
    vf2 xc2 = {xa.z, xb.z}, xc3 = {xa.w, xb.w};
    vf2 a0 = {bias[0], bias[0]}, a1 = {bias[1], bias[1]};
    vf2 a2 = {bias[2], bias[2]}, a3 = {bias[3], bias[3]};
    a0 += wf[0][0] * xc0 + wf[0][1] * xc1 + wf[0][2] * xc2 + wf[0][3] * xc3;
    a1 += wf[1][0] * xc0 + wf[1][1] * xc1 + wf[1][2] * xc2 + wf[1][3] * xc3;
    a2 += wf[2][0] * xc0 + wf[2][1] * xc1 + wf[2][2] * xc2 + wf[2][3] * xc3;
    a3 += wf[3][0] * xc0 + wf[3][1] * xc1 + wf[3][2] * xc2 + wf[3][3] * xc3;
#pragma unroll
    for (int mm = 0; mm < 4; mm++) {
      vf2 hm0 = sh[sub][mm * 4 + 0];
      vf2 hm1 = sh[sub][mm * 4 + 1];
      vf2 hm2 = sh[sub][mm * 4 + 2];
      vf2 hm3 = sh[sub][mm * 4 + 3];
      a0 += whh[0][mm * 4 + 0] * hm0 + whh[0][mm * 4 + 1] * hm1 +
            whh[0][mm * 4 + 2] * hm2 + whh[0][mm * 4 + 3] * hm3;
      a1 += whh[1][mm * 4 + 0] * hm0 + whh[1][mm * 4 + 1] * hm1 +
            whh[1][mm * 4 + 2] * hm2 + whh[1][mm * 4 + 3] * hm3;
      a2 += whh[2][mm * 4 + 0] * hm0 + whh[2][mm * 4 + 1] * hm1 +
            whh[2][mm * 4 + 2] * hm2 + whh[2][mm * 4 + 3] * hm3;
      a3 += whh[3][mm * 4 + 0] * hm0 + whh[3][mm * 4 + 1] * hm1 +
            whh[3][mm * 4 + 2] * hm2 + whh[3][mm * 4 + 3] * hm3;
    }
    vf2 ig, fg, gg, og, tc;
    ig.x = sigmoidf_(a0.x); ig.y = sigmoidf_(a0.y);
    fg.x = sigmoidf_(a1.x); fg.y = sigmoidf_(a1.y);
    gg.x = tanhf_(a2.x);    gg.y = tanhf_(a2.y);
    og.x = sigmoidf_(a3.x); og.y = sigmoidf_(a3.y);
    c = fg * c + ig * gg;
    tc.x = tanhf_(c.x);     tc.y = tanhf_(c.y);
    h = og * tc;
    __syncthreads();
    sh[sub][k] = h;
  }
  h_out[(size_t)row * 16 + k] = h.x;
  h_out[(size_t)(row + 1) * 16 + k] = h.y;
}

// ---------------------------------------------------------------------------
// Prep: pack conv weights into MFMA A-fragment order (bf16).
// Sets 0..14: cc convs (unchanged).
// Sets 15..21: d1/d2 of stages 2/3 as matmul A-frags, K-order k=jt*CIeff+ci,
// zero-padded past K=3*CIeff (so B needs no masking in the pad region):
//   15: s2 d1 (CIw=8,  CIeff=8,  kk=0)   16,17: s2 d2 (CIw=16, kk=0,1)
//   18,19: s3 d1 (CIw=16, kk=0,1)        20,21: s3 d2 (CIw=16, kk=0,1)
// ---------------------------------------------------------------------------
__global__ void prep_kernel(const float* __restrict__ t1c,
                            const float* __restrict__ t2c,
                            const float* __restrict__ t3c,
                            const float* __restrict__ t2d1,
                            const float* __restrict__ t2d2,
                            const float* __restrict__ t3d1,
                            const float* __restrict__ t3d2,
                            unsigned short* __restrict__ apk) {
  const int L = threadIdx.x;  // 64 threads
  const int co = L & 15, q = L >> 4;
#pragma unroll 1
  for (int set = 0; set < 15; set++) {
    int s, p;
    if (set < 3) { s = 0; p = set; }
    else if (set < 9) { s = 1; p = set - 3; }
    else { s = 2; p = set - 9; }
    u8v f;
#pragma unroll
    for (int j = 0; j < 8; j++) {
      float val = 0.f;
      if (s == 0) {
        int dn = p * 4 + q, ci = j;
        if (co < 8 && dn < 11) val = t1c[(co * 8 + ci) * 11 + dn];
      } else {
        int dn = p * 2 + (q >> 1), ci = (q & 1) * 8 + j;
        const float* w = (s == 1) ? t2c : t3c;
        if (dn < 11) val = w[(co * 16 + ci) * 11 + dn];
      }
      f[j] = f2bf(val);
    }
    *(u8v*)&apk[(set * 64 + L) * 8] = f;
  }
#pragma unroll 1
  for (int ds = 0; ds < 7; ds++) {
    const float* w; int CIw, CIeff, kk;
    switch (ds) {
      case 0: w = t2d1; CIw = 8;  CIeff = 8;  kk = 0; break;
      case 1: w = t2d2; CIw = 16; CIeff = 16; kk = 0; break;
      case 2: w = t2d2; CIw = 16; CIeff = 16; kk = 1; break;
      case 3: w = t3d1; CIw = 16; CIeff = 16; kk = 0; break;
      case 4: w = t3d1; CIw = 16; CIeff = 16; kk = 1; break;
      case 5: w = t3d2; CIw = 16; CIeff = 16; kk = 0; break;
      default: w = t3d2; CIw = 16; CIeff = 16; kk = 1; break;
    }
    u8v f;
#pragma unroll
    for (int j = 0; j < 8; j++) {
      int kg = kk * 32 + q * 8 + j;
      int ci = kg % CIeff, jt = kg / CIeff;
      float val = (jt < 3) ? w[(co * CIw + ci) * 3 + jt] : 0.f;
      f[j] = f2bf(val);
    }
    *(u8v*)&apk[((15 + ds) * 64 + L) * 8] = f;
  }
}

// ---------------------------------------------------------------------------
// K2 (stage 1 only): fused d1+d2, proj folded, fp32 x input, bf16
// channel-interleaved output [by][n][t][8]. R5-proven scalar streaming.
// ---------------------------------------------------------------------------
__global__ __launch_bounds__(128) void d12a_kernel(
    const float* __restrict__ xin,
    const float* __restrict__ pw, const float* __restrict__ pb,
    const float* __restrict__ w1,  // [8][4][3]
    const float* __restrict__ w2,  // [8][8][3]
    unsigned short* __restrict__ out, int b0) {
  constexpr int CI = 4, CO = 8, DIL = 1;
  const int t = threadIdx.x;
  const int n = swz_n(blockIdx.x), by = blockIdx.y;
  const int b = b0 + by;

  float r1[3][CO];
#pragma unroll
  for (int u = 0; u < 3; u++)
#pragma unroll
    for (int co = 0; co < CO; co++) r1[u][co] = 0.f;

  const float4* xp = (const float4*)xin + ((size_t)b * N + n) * T;
  float px[5][4];
#pragma unroll
  for (int v = 0; v < 5; v++) {
    int idx = t - v * DIL;
    float4 xr = xp[idx < 0 ? 0 : idx];
    bool ok = idx >= 0;
    px[v][0] = ok ? pb[0] + pw[0] * xr.x + pw[1] * xr.y + pw[2] * xr.z + pw[3] * xr.w : 0.f;
    px[v][1] = ok ? pb[1] + pw[4] * xr.x + pw[5] * xr.y + pw[6] * xr.z + pw[7] * xr.w : 0.f;
    px[v][2] = ok ? pb[2] + pw[8] * xr.x + pw[9] * xr.y + pw[10] * xr.z + pw[11] * xr.w : 0.f;
    px[v][3] = ok ? pb[3] + pw[12] * xr.x + pw[13] * xr.y + pw[14] * xr.z + pw[15] * xr.w : 0.f;
  }
#pragma unroll
  for (int ci = 0; ci < CI; ci++) {
#pragma unroll
    for (int j = 0; j < 3; j++) {
#pragma unroll
      for (int co = 0; co < CO; co++) {
        float w = w1[(co * CI + ci) * 3 + j];
#pragma unroll
        for (int u = 0; u < 3; u++) r1[u][co] += w * px[u + 2 - j][ci];
      }
    }
  }
#pragma unroll
  for (int u = 0; u < 3; u++)
#pragma unroll
    for (int co = 0; co < CO; co++) r1[u][co] = fmaxf(r1[u][co], 0.f);

  float acc[CO];
#pragma unroll
  for (int co = 0; co < CO; co++) acc[co] = 0.f;
#pragma unroll
  for (int cm = 0; cm < CO; cm++) {
#pragma unroll
    for (int j = 0; j < 3; j++) {
#pragma unroll
      for (int co = 0; co < CO; co++)
        acc[co] += w2[(co * CO + cm) * 3 + j] * r1[2 - j][cm];
    }
  }
  unsigned short* op = &out[(((size_t)by * N + n) * T + t) * CO];
  u8v a;
#pragma unroll
  for (int j = 0; j < 8; j++) a[j] = f2bf(fmaxf(acc[j], 0.f));
  *(u8v*)&op[0] = a;
}

// ---------------------------------------------------------------------------
// K4/K6 (stages 2/3) REWRITE (d12m): both dilated convs as MFMA matmuls,
// mirroring the proven ccm pattern (same A-prepack / B-gather / C/D layout).
//   out[co][t] = sum_{ci,jt} W[co][jt*CIeff+ci] * X[ci][t - DIL*jt]
// M=16 co rows, 16 t-cols per tile, K=3*CIeff padded to 32/64 (A zero-pad).
// One wave per (n,by): stage X fp32->bf16 LDS (halo 8 zeros = causal pad),
// d1 8 tiles -> relu -> LDS, d2 8 tiles -> relu -> bf16 out [by][n][t][16].
// Replaces d12v (measured ~128 us/dispatch; in-loop weight-load stalls).
// ---------------------------------------------------------------------------
template <int CI, int DIL>
__global__ __launch_bounds__(64) void d12m_kernel(
    const float* __restrict__ xin,           // [Bc][CI][N][T] fp32
    const unsigned short* __restrict__ apk,  // stage base: d1 sets, then d2
    unsigned short* __restrict__ out) {      // [Bc][n][t][16] bf16
  constexpr int HALO = 8;
  __shared__ __align__(16) unsigned short Xs[HALO + T][16];
  __shared__ __align__(16) unsigned short Rs[HALO + T][16];
  const int l = threadIdx.x;
  const int tcol = l & 15, q = l >> 4;
  const int n = swz_n(blockIdx.x), by = blockIdx.y;

  // zero halos (causal zero-pad; d2's tap reach 2*DIL <= 8)
  if (l < 16) {
    *(u8v*)&Xs[l >> 1][(l & 1) * 8] = (u8v)0;
  } else if (l < 32) {
    const int m = l - 16;
    *(u8v*)&Rs[m >> 1][(m & 1) * 8] = (u8v)0;
  }
  // stage X -> bf16 LDS (coalesced fp32 reads)
#pragma unroll
  for (int ci = 0; ci < CI; ci++) {
    const float* xp = xin + (((size_t)by * CI + ci) * N + n) * T;
#pragma unroll
    for (int hh = 0; hh < 2; hh++) {
      const int t = hh * 64 + l;
      Xs[HALO + t][ci] = f2bf(xp[t]);
    }
  }
  __syncthreads();

  // A fragments (prepacked; pad region is zeros so B garbage is harmless)
  s8v a1_0, a1_1, a2_0, a2_1;
  constexpr int ND1 = (CI == 8) ? 1 : 2;
  a1_0 = *(const s8v*)&apk[(0 * 64 + l) * 8];
  if constexpr (CI == 16) a1_1 = *(const s8v*)&apk[(1 * 64 + l) * 8];
  a2_0 = *(const s8v*)&apk[((ND1 + 0) * 64 + l) * 8];
  a2_1 = *(const s8v*)&apk[((ND1 + 1) * 64 + l) * 8];

  // ---- d1: 8 t-tiles ----
#pragma unroll 1
  for (int tt = 0; tt < 8; tt++) {
    const int t = tt * 16 + tcol;
    f4v acc = (f4v)0.f;
    if constexpr (CI == 8) {
      // K=24 in one MFMA (k = jt*8+ci): lane-group q is tap jt (q==3 is pad)
      const int jt = (q < 3) ? q : 2;
      s8v bf = *(const s8v*)&Xs[HALO + t - DIL * jt][0];
      acc = __builtin_amdgcn_mfma_f32_16x16x32_bf16(a1_0, bf, acc, 0, 0, 0);
    } else {
      // K=48 in two MFMAs (k = jt*16+ci)
      {
        const int jt = q >> 1, ci0 = (q & 1) * 8;
        s8v bf = *(const s8v*)&Xs[HALO + t - DIL * jt][ci0];
        acc = __builtin_amdgcn_mfma_f32_16x16x32_bf16(a1_0, bf, acc, 0, 0, 0);
      }
      {
        const int ci0 = (q & 1) * 8;  // jt=2 for q<2; pad (A zeros) for q>=2
        s8v bf = *(const s8v*)&Xs[HALO + t - DIL * 2][ci0];
        acc = __builtin_amdgcn_mfma_f32_16x16x32_bf16(a1_1, bf, acc, 0, 0, 0);
      }
    }
    // lane holds out1[cm=q*4+r][t]: relu -> bf16 -> LDS
    u4s rb;
#pragma unroll
    for (int r = 0; r < 4; r++) rb[r] = f2bf(fmaxf(acc[r], 0.f));
    *(u4s*)&Rs[HALO + t][q * 4] = rb;
  }
  __syncthreads();

  // ---- d2: 8 t-tiles (K=48, k = jt*16+cm) ----
  unsigned short* opb = &out[(((size_t)by * N + n) * T) * 16];
#pragma unroll 1
  for (int tt = 0; tt < 8; tt++) {
    const int t = tt * 16 + tcol;
    f4v acc = (f4v)0.f;
    {
      const int jt = q >> 1, ci0 = (q & 1) * 8;
      s8v bf = *(const s8v*)&Rs[HALO + t - DIL * jt][ci0];
      acc = __builtin_amdgcn_mfma_f32_16x16x32_bf16(a2_0, bf, acc, 0, 0, 0);
    }
    {
      const int ci0 = (q & 1) * 8;  // jt=2 for q<2; pad (A zeros) otherwise
      s8v bf = *(const s8v*)&Rs[HALO + t - DIL * 2][ci0];
      acc = __builtin_amdgcn_mfma_f32_16x16x32_bf16(a2_1, bf, acc, 0, 0, 0);
    }
    u4s ob;
#pragma unroll
    for (int r = 0; r < 4; r++) ob[r] = f2bf(fmaxf(acc[r], 0.f));
    *(u4s*)&opb[(size_t)t * 16 + q * 4] = ob;
  }
}

// ---------------------------------------------------------------------------
// K3/K5/K7: cross-stock 11x1 conv via MFMA (R10 version: fp32 out/residual).
// RESMODE: 0 = x-proj+rw (C=8), 1 = rw from fp32 H, 2 = identity fp32 H.
// ---------------------------------------------------------------------------
template <int C, int CIR, int RESMODE>
__global__ __launch_bounds__(64) void ccm_kernel(
    const unsigned short* __restrict__ zin,  // [Bc][N][T][C] bf16
    const unsigned short* __restrict__ apk,  // [NMF][64][8] bf16
    const float* __restrict__ resin,         // RESMODE 0: x; else fp32 planar
    const float* __restrict__ rw,
    const float* __restrict__ pw, const float* __restrict__ pb,
    float* __restrict__ out,                 // fp32 planar [Bc][C][N][T]
    int b0) {
  constexpr int NMF = (C == 8) ? 3 : 6;
  const int L = threadIdx.x;
  const int tcol = L & 15, q = L >> 4;
  const int n = swz_n(blockIdx.x);
  const int t = blockIdx.y * 16 + tcol;
  const int by = blockIdx.z;
  const int b = b0 + by;

  f4v d = {0.f, 0.f, 0.f, 0.f};
#pragma unroll
  for (int p = 0; p < NMF; p++) {
    int dn = (C == 8) ? (p * 4 + q) : (p * 2 + (q >> 1));
    int row = n + dn - 5;
    bool ok = (unsigned)row < (unsigned)N;
    int rowc = ok ? row : 0;
    const unsigned short* bp =
        &zin[(((size_t)by * N + rowc) * T + t) * C + ((C == 16) ? (q & 1) * 8 : 0)];
    s8v bfrag = *(const s8v*)bp;
    if (!ok) bfrag = (s8v){0, 0, 0, 0, 0, 0, 0, 0};
    s8v afrag = *(const s8v*)&apk[(p * 64 + L) * 8];
    d = __builtin_amdgcn_mfma_f32_16x16x32_bf16(afrag, bfrag, d, 0, 0, 0);
  }

  if (C == 8 && q >= 2) return;

  float y[4];
  if constexpr (RESMODE == 0) {
    float4 xr = ((const float4*)resin)[((size_t)b * N + n) * T + t];
    float xv[4];
#pragma unroll
    for (int j = 0; j < 4; j++)
      xv[j] = pb[j] + pw[j * 4 + 0] * xr.x + pw[j * 4 + 1] * xr.y +
              pw[j * 4 + 2] * xr.z + pw[j * 4 + 3] * xr.w;
#pragma unroll
    for (int r = 0; r < 4; r++) {
      int co = q * 4 + r;
      float rv = rw[co * 4 + 0] * xv[0] + rw[co * 4 + 1] * xv[1] +
                 rw[co * 4 + 2] * xv[2] + rw[co * 4 + 3] * xv[3];
      y[r] = fmaxf(rv + fmaxf(d[r], 0.f), 0.f);
    }
  } else if constexpr (RESMODE == 1) {
    float hv[CIR];
#pragma unroll
    for (int ci = 0; ci < CIR; ci++)
      hv[ci] = resin[(((size_t)by * CIR + ci) * N + n) * T + t];
#pragma unroll
    for (int r = 0; r < 4; r++) {
      int co = q * 4 + r;
      float rv = 0.f;
#pragma unroll
      for (int ci = 0; ci < CIR; ci++) rv += rw[co * CIR + ci] * hv[ci];
      y[r] = fmaxf(rv + fmaxf(d[r], 0.f), 0.f);
    }
  } else {
#pragma unroll
    for (int r = 0; r < 4; r++) {
      int co = q * 4 + r;
      float rv = resin[(((size_t)by * C + co) * N + n) * T + t];
      y[r] = fmaxf(rv + fmaxf(d[r], 0.f), 0.f);
    }
  }
#pragma unroll
  for (int r = 0; r < 4; r++) {
    int co = q * 4 + r;
    out[(((size_t)by * C + co) * N + n) * T + t] = y[r];
  }
}

// ---------------------------------------------------------------------------
// conv4: h4[b][o][n] = relu(sum_{ci,t} w4[o][ci][t] * Y[ci][t]).
// One 64-lane wave per (b,n); Y fp32 planar (R10 version).
// ---------------------------------------------------------------------------
__global__ __launch_bounds__(64) void conv4_kernel(
    const float* __restrict__ Y,   // [Bc][16][N][T]
    const float* __restrict__ w4,  // [16][16][T]
    float* __restrict__ h4,        // [B][16][N]
    int b0) {
  const int tl = threadIdx.x;
  const int n = swz_n(blockIdx.x), by = blockIdx.y;
  const int b = b0 + by;
  const int t0 = tl * 2;

  vf2 y[16];
#pragma unroll
  for (int ci = 0; ci < 16; ci++)
    y[ci] = *(const vf2*)&Y[(((size_t)by * 16 + ci) * N + n) * T + t0];

#pragma unroll 1
  for (int o = 0; o < 16; o++) {
    vf2 s = (vf2)0.f;
#pragma unroll
    for (int ci = 0; ci < 16; ci++) {
      vf2 w = *(const vf2*)&w4[(size_t)(o * 16 + ci) * T + t0];
      s += w * y[ci];
    }
    float sum = s.x + s.y;
    sum += __shfl_down(sum, 32);
    sum += __shfl_down(sum, 16);
    sum += __shfl_down(sum, 8);
    sum += __shfl_down(sum, 4);
    sum += __shfl_down(sum, 2);
    sum += __shfl_down(sum, 1);
    if (tl == 0) h4[((size_t)b * 16 + o) * N + n] = fmaxf(sum, 0.f);
  }
}

// ---------------------------------------------------------------------------
// K8: logits (torch reshape scramble) + softmax over N
// ---------------------------------------------------------------------------
__global__ __launch_bounds__(128) void final_kernel(
    const float* __restrict__ hl, const float* __restrict__ h4,
    const float* __restrict__ ow, const float* __restrict__ ob,
    float* __restrict__ out) {
  __shared__ float red[128];
  int b = blockIdx.x, n = threadIdx.x;
  bool valid = n < N;
  float lv = 0.f;
  if (valid) {
    int idx = b * N + n;
    int sb = idx & (B - 1);
    int sn = idx >> 8;
    const float* h = &hl[((size_t)sb * N + sn) * 16];
    float a = ob[0];
#pragma unroll
    for (int k = 0; k < 16; k++) a += h[k] * ow[k];
#pragma unroll
    for (int c = 0; c < 16; c++) a += h4[((size_t)b * 16 + c) * N + n] * ow[16 + c];
    lv = a;
  }
  red[n] = valid ? lv : -1e30f;
  __syncthreads();
  for (int off = 64; off > 0; off >>= 1) {
    if (n < off) red[n] = fmaxf(red[n], red[n + off]);
    __syncthreads();
  }
  float m = red[0];
  __syncthreads();
  float e = valid ? __expf(lv - m) : 0.f;
  red[n] = e;
  __syncthreads();
  for (int off = 64; off > 0; off >>= 1) {
    if (n < off) red[n] += red[n + off];
    __syncthreads();
  }
  float s = red[0];
  if (valid) out[(size_t)b * N + n] = e / s;
}

// ---------------------------------------------------------------------------
// Launch. Chunked over B. Per-b unit: Zb1(bf16 8ch=4) + H1(fp32 8ch=8) +
// Zb2(bf16 16ch=8) + H2(fp32 16) + Y3(fp32 16) = 52 NT-floats.
// apk region: 22 MFMA A-frag sets * 512 ushorts = 11264 ushorts (8192 floats).
// ---------------------------------------------------------------------------
extern "C" void kernel_launch(void* const* d_in, const int* in_sizes, int n_in,
                              void* d_out, int out_size, void* d_ws, size_t ws_size,
                              hipStream_t stream) {
  const float* x    = (const float*)d_in[0];
  const float* pw   = (const float*)d_in[1];
  const float* pb   = (const float*)d_in[2];
  const float* w_ih = (const float*)d_in[3];
  const float* w_hh = (const float*)d_in[4];
  const float* b_ih = (const float*)d_in[5];
  const float* b_hh = (const float*)d_in[6];
  const float* t1d1 = (const float*)d_in[7];
  const float* t1d2 = (const float*)d_in[8];
  const float* t1c  = (const float*)d_in[9];
  const float* t1r  = (const float*)d_in[10];
  const float* t2d1 = (const float*)d_in[11];
  const float* t2d2 = (const float*)d_in[12];
  const float* t2c  = (const float*)d_in[13];
  const float* t2r  = (const float*)d_in[14];
  const float* t3d1 = (const float*)d_in[15];
  const float* t3d2 = (const float*)d_in[16];
  const float* t3c  = (const float*)d_in[17];
  const float* w4   = (const float*)d_in[18];
  const float* ow   = (const float*)d_in[19];
  const float* ob   = (const float*)d_in[20];
  float* outp = (float*)d_out;

  const size_t NT = (size_t)N * T;            // 12928
  const size_t Bn16 = (size_t)B * N * 16;
  const size_t unit = 52 * NT;                // floats per chunked b
  const size_t fixed = 2 * Bn16 + 8192;       // hl + h4 + apk

  int Bc = 4;
  const int cands[7] = {256, 128, 64, 32, 16, 8, 4};
  for (int i = 0; i < 7; i++) {
    if ((cands[i] * unit + fixed) * sizeof(float) <= ws_size) { Bc = cands[i]; break; }
  }

  float* ws = (float*)d_ws;
  float* hl = ws;                              // [B*N][16]
  float* h4 = hl + Bn16;                       // [B][16][N]
  unsigned short* apk = (unsigned short*)(h4 + Bn16);  // 22*512 ushorts
  float* base = h4 + Bn16 + 8192;
  unsigned short* Zb1 = (unsigned short*)base;            // [Bc][N][T][8] bf16
  float* H1 = base + (size_t)Bc * 4 * NT;                 // [Bc][8][N][T]
  unsigned short* Zb2 = (unsigned short*)(H1 + (size_t)Bc * 8 * NT);  // [Bc][N][T][16]
  float* H2 = H1 + (size_t)Bc * 16 * NT;                  // [Bc][16][N][T]
  float* Y3 = H2 + (size_t)Bc * 16 * NT;                  // [Bc][16][N][T]

  prep_kernel<<<1, 64, 0, stream>>>(t1c, t2c, t3c, t2d1, t2d2, t3d1, t3d2, apk);
  lstm_kernel<<<(B * N) / 8, 64, 0, stream>>>(x, pw, pb, w_ih, w_hh, b_ih,
                                              b_hh, hl);

  dim3 g(N, Bc);
  dim3 gm(N, T / 16, Bc);
  for (int b0 = 0; b0 < B; b0 += Bc) {
    d12a_kernel<<<g, 128, 0, stream>>>(x, pw, pb, t1d1, t1d2, Zb1, b0);
    ccm_kernel<8, 4, 0><<<gm, 64, 0, stream>>>(
        Zb1, apk + 0 * 512, x, t1r, pw, pb, H1, b0);

    d12m_kernel<8, 2><<<g, 64, 0, stream>>>(H1, apk + 15 * 512, Zb2);
    ccm_kernel<16, 8, 1><<<gm, 64, 0, stream>>>(
        Zb2, apk + 3 * 512, H1, t2r, pw, pb, H2, b0);

    d12m_kernel<16, 4><<<g, 64, 0, stream>>>(H2, apk + 18 * 512, Zb2);
    ccm_kernel<16, 16, 2><<<gm, 64, 0, stream>>>(
        Zb2, apk + 9 * 512, H2, nullptr, pw, pb, Y3, b0);

    conv4_kernel<<<g, 64, 0, stream>>>(Y3, w4, h4, b0);
  }

  final_kernel<<<B, 128, 0, stream>>>(hl, h4, ow, ob, outp);
}

// Round 5
// 936.394 us; speedup vs baseline: 2.3619x; 1.1715x over previous
//
#include <hip/hip_runtime.h>
#include <hip/hip_bf16.h>

// ---------------------------------------------------------------------------
// Problem constants (reference: B,N,T,P,H = 256,101,128,4,16)
// ---------------------------------------------------------------------------
constexpr int B = 256;
constexpr int N = 101;
constexpr int T = 128;

typedef float vf2 __attribute__((ext_vector_type(2)));
typedef short s8v __attribute__((ext_vector_type(8)));    // 8 bf16 (4 VGPRs)
typedef unsigned short u8v __attribute__((ext_vector_type(8)));
typedef unsigned short u4s __attribute__((ext_vector_type(4)));
typedef float f4v __attribute__((ext_vector_type(4)));    // MFMA accum

__device__ __forceinline__ float frcp(float x) { return __builtin_amdgcn_rcpf(x); }
__device__ __forceinline__ float sigmoidf_(float x) { return frcp(1.f + __expf(-x)); }
__device__ __forceinline__ float tanhf_(float x) { return 2.f * frcp(1.f + __expf(-2.f * x)) - 1.f; }

// fp32 -> bf16 bits, round-nearest-even
__device__ __forceinline__ unsigned short f2bf(float x) {
  unsigned int u = __float_as_uint(x);
  u = (u + 0x7FFFu + ((u >> 16) & 1u)) >> 16;
  return (unsigned short)u;
}
// bf16 bits -> fp32
__device__ __forceinline__ float bf2f(unsigned short u) {
  return __uint_as_float((unsigned int)u << 16);
}

// XCD-aware n-swizzle (R7: cut cc FETCH 605->140 MB). Bijection on [0,101).
__device__ __forceinline__ int swz_n(int L) {
  int q = L & 7, r = L >> 3;
  return q * 13 - (q > 5 ? (q - 5) : 0) + r;
}

// ---------------------------------------------------------------------------
// K1: LSTM. R0 structure + proj fold (measured ~208 us; best of 3 variants).
// 8 seqs/wave (sub=lane>>4 owns a vf2 seq-pair), h via per-sub LDS row.
// ---------------------------------------------------------------------------
__global__ __launch_bounds__(64) void lstm_kernel(
    const float* __restrict__ x, const float* __restrict__ pw,
    const float* __restrict__ pb, const float* __restrict__ w_ih,
    const float* __restrict__ w_hh, const float* __restrict__ b_ih,
    const float* __restrict__ b_hh, float* __restrict__ h_out) {
  __shared__ vf2 sh[4][16];  // [sub][unit] -> (rowA, rowB)
  const int lane = threadIdx.x;
  const int sub = lane >> 4;
  const int k = lane & 15;
  const int row = blockIdx.x * 8 + sub * 2;  // 3232*8 = 25856

  float wf[4][4], whh[4][16], bias[4];
#pragma unroll
  for (int q = 0; q < 4; q++) {
    const int j = q * 16 + k;  // gate order i,f,g,o
    float bp = b_ih[j] + b_hh[j];
#pragma unroll
    for (int c = 0; c < 4; c++) bp += w_ih[j * 4 + c] * pb[c];
    bias[q] = bp;
#pragma unroll
    for (int p = 0; p < 4; p++) {
      float s = 0.f;
#pragma unroll
      for (int c = 0; c < 4; c++) s += w_ih[j * 4 + c] * pw[c * 4 + p];
      wf[q][p] = s;
    }
#pragma unroll
    for (int m = 0; m < 16; m++) whh[q][m] = w_hh[j * 16 + m];
  }

  vf2 h = {0.f, 0.f}, c = {0.f, 0.f};
  sh[sub][k] = h;
  const float4* xpA = (const float4*)x + (size_t)row * T;
  const float4* xpB = xpA + T;

#pragma unroll 1
  for (int t = 0; t < T; t++) {
    __syncthreads();
    float4 xa = xpA[t];
    float4 xb = xpB[t];
    vf2 xc0 = {xa.x, xb.x}, xc1 = {xa.y, xb.y};
    vf2 xc2 = {xa.z, xb.z}, xc3 = {xa.w, xb.w};
    vf2 a0 = {bias[0], bias[0]}, a1 = {bias[1], bias[1]};
    vf2 a2 = {bias[2], bias[2]}, a3 = {bias[3], bias[3]};
    a0 += wf[0][0] * xc0 + wf[0][1] * xc1 + wf[0][2] * xc2 + wf[0][3] * xc3;
    a1 += wf[1][0] * xc0 + wf[1][1] * xc1 + wf[1][2] * xc2 + wf[1][3] * xc3;
    a2 += wf[2][0] * xc0 + wf[2][1] * xc1 + wf[2][2] * xc2 + wf[2][3] * xc3;
    a3 += wf[3][0] * xc0 + wf[3][1] * xc1 + wf[3][2] * xc2 + wf[3][3] * xc3;
#pragma unroll
    for (int mm = 0; mm < 4; mm++) {
      vf2 hm0 = sh[sub][mm * 4 + 0];
      vf2 hm1 = sh[sub][mm * 4 + 1];
      vf2 hm2 = sh[sub][mm * 4 + 2];
      vf2 hm3 = sh[sub][mm * 4 + 3];
      a0 += whh[0][mm * 4 + 0] * hm0 + whh[0][mm * 4 + 1] * hm1 +
            whh[0][mm * 4 + 2] * hm2 + whh[0][mm * 4 + 3] * hm3;
      a1 += whh[1][mm * 4 + 0] * hm0 + whh[1][mm * 4 + 1] * hm1 +
            whh[1][mm * 4 + 2] * hm2 + whh[1][mm * 4 + 3] * hm3;
      a2 += whh[2][mm * 4 + 0] * hm0 + whh[2][mm * 4 + 1] * hm1 +
            whh[2][mm * 4 + 2] * hm2 + whh[2][mm * 4 + 3] * hm3;
      a3 += whh[3][mm * 4 + 0] * hm0 + whh[3][mm * 4 + 1] * hm1 +
            whh[3][mm * 4 + 2] * hm2 + whh[3][mm * 4 + 3] * hm3;
    }
    vf2 ig, fg, gg, og, tc;
    ig.x = sigmoidf_(a0.x); ig.y = sigmoidf_(a0.y);
    fg.x = sigmoidf_(a1.x); fg.y = sigmoidf_(a1.y);
    gg.x = tanhf_(a2.x);    gg.y = tanhf_(a2.y);
    og.x = sigmoidf_(a3.x); og.y = sigmoidf_(a3.y);
    c = fg * c + ig * gg;
    tc.x = tanhf_(c.x);     tc.y = tanhf_(c.y);
    h = og * tc;
    __syncthreads();
    sh[sub][k] = h;
  }
  h_out[(size_t)row * 16 + k] = h.x;
  h_out[(size_t)(row + 1) * 16 + k] = h.y;
}

// ---------------------------------------------------------------------------
// Prep: pack conv weights into MFMA A-fragment order (bf16).
// Sets 0..14: cc convs. Sets 15..21: d1/d2 of stages 2/3 (K=jt*CIeff+ci,
// zero-padded past K=3*CIeff so the B pad region needs no masking):
//   15: s2 d1 (CIw=8)   16,17: s2 d2   18,19: s3 d1   20,21: s3 d2
// ---------------------------------------------------------------------------
__global__ void prep_kernel(const float* __restrict__ t1c,
                            const float* __restrict__ t2c,
                            const float* __restrict__ t3c,
                            const float* __restrict__ t2d1,
                            const float* __restrict__ t2d2,
                            const float* __restrict__ t3d1,
                            const float* __restrict__ t3d2,
                            unsigned short* __restrict__ apk) {
  const int L = threadIdx.x;  // 64 threads
  const int co = L & 15, q = L >> 4;
#pragma unroll 1
  for (int set = 0; set < 15; set++) {
    int s, p;
    if (set < 3) { s = 0; p = set; }
    else if (set < 9) { s = 1; p = set - 3; }
    else { s = 2; p = set - 9; }
    u8v f;
#pragma unroll
    for (int j = 0; j < 8; j++) {
      float val = 0.f;
      if (s == 0) {
        int dn = p * 4 + q, ci = j;
        if (co < 8 && dn < 11) val = t1c[(co * 8 + ci) * 11 + dn];
      } else {
        int dn = p * 2 + (q >> 1), ci = (q & 1) * 8 + j;
        const float* w = (s == 1) ? t2c : t3c;
        if (dn < 11) val = w[(co * 16 + ci) * 11 + dn];
      }
      f[j] = f2bf(val);
    }
    *(u8v*)&apk[(set * 64 + L) * 8] = f;
  }
#pragma unroll 1
  for (int ds = 0; ds < 7; ds++) {
    const float* w; int CIw, CIeff, kk;
    switch (ds) {
      case 0: w = t2d1; CIw = 8;  CIeff = 8;  kk = 0; break;
      case 1: w = t2d2; CIw = 16; CIeff = 16; kk = 0; break;
      case 2: w = t2d2; CIw = 16; CIeff = 16; kk = 1; break;
      case 3: w = t3d1; CIw = 16; CIeff = 16; kk = 0; break;
      case 4: w = t3d1; CIw = 16; CIeff = 16; kk = 1; break;
      case 5: w = t3d2; CIw = 16; CIeff = 16; kk = 0; break;
      default: w = t3d2; CIw = 16; CIeff = 16; kk = 1; break;
    }
    u8v f;
#pragma unroll
    for (int j = 0; j < 8; j++) {
      int kg = kk * 32 + q * 8 + j;
      int ci = kg % CIeff, jt = kg / CIeff;
      float val = (jt < 3) ? w[(co * CIw + ci) * 3 + jt] : 0.f;
      f[j] = f2bf(val);
    }
    *(u8v*)&apk[((15 + ds) * 64 + L) * 8] = f;
  }
}

// ---------------------------------------------------------------------------
// K2 (stage 1 only): fused d1+d2, proj folded, fp32 x input, bf16
// channel-interleaved output [by][n][t][8]. R5-proven scalar streaming.
// ---------------------------------------------------------------------------
__global__ __launch_bounds__(128) void d12a_kernel(
    const float* __restrict__ xin,
    const float* __restrict__ pw, const float* __restrict__ pb,
    const float* __restrict__ w1,  // [8][4][3]
    const float* __restrict__ w2,  // [8][8][3]
    unsigned short* __restrict__ out, int b0) {
  constexpr int CI = 4, CO = 8, DIL = 1;
  const int t = threadIdx.x;
  const int n = swz_n(blockIdx.x), by = blockIdx.y;
  const int b = b0 + by;

  float r1[3][CO];
#pragma unroll
  for (int u = 0; u < 3; u++)
#pragma unroll
    for (int co = 0; co < CO; co++) r1[u][co] = 0.f;

  const float4* xp = (const float4*)xin + ((size_t)b * N + n) * T;
  float px[5][4];
#pragma unroll
  for (int v = 0; v < 5; v++) {
    int idx = t - v * DIL;
    float4 xr = xp[idx < 0 ? 0 : idx];
    bool ok = idx >= 0;
    px[v][0] = ok ? pb[0] + pw[0] * xr.x + pw[1] * xr.y + pw[2] * xr.z + pw[3] * xr.w : 0.f;
    px[v][1] = ok ? pb[1] + pw[4] * xr.x + pw[5] * xr.y + pw[6] * xr.z + pw[7] * xr.w : 0.f;
    px[v][2] = ok ? pb[2] + pw[8] * xr.x + pw[9] * xr.y + pw[10] * xr.z + pw[11] * xr.w : 0.f;
    px[v][3] = ok ? pb[3] + pw[12] * xr.x + pw[13] * xr.y + pw[14] * xr.z + pw[15] * xr.w : 0.f;
  }
#pragma unroll
  for (int ci = 0; ci < CI; ci++) {
#pragma unroll
    for (int j = 0; j < 3; j++) {
#pragma unroll
      for (int co = 0; co < CO; co++) {
        float w = w1[(co * CI + ci) * 3 + j];
#pragma unroll
        for (int u = 0; u < 3; u++) r1[u][co] += w * px[u + 2 - j][ci];
      }
    }
  }
#pragma unroll
  for (int u = 0; u < 3; u++)
#pragma unroll
    for (int co = 0; co < CO; co++) r1[u][co] = fmaxf(r1[u][co], 0.f);

  float acc[CO];
#pragma unroll
  for (int co = 0; co < CO; co++) acc[co] = 0.f;
#pragma unroll
  for (int cm = 0; cm < CO; cm++) {
#pragma unroll
    for (int j = 0; j < 3; j++) {
#pragma unroll
      for (int co = 0; co < CO; co++)
        acc[co] += w2[(co * CO + cm) * 3 + j] * r1[2 - j][cm];
    }
  }
  unsigned short* op = &out[(((size_t)by * N + n) * T + t) * CO];
  u8v a;
#pragma unroll
  for (int j = 0; j < 8; j++) a[j] = f2bf(fmaxf(acc[j], 0.f));
  *(u8v*)&op[0] = a;
}

// ---------------------------------------------------------------------------
// K4/K6 (stages 2/3) d12m v2: NO X-staging. Input is bf16 channel-interleaved
// [Bc][n][t][CI], so B-fragments load DIRECTLY from global (per-n slab is
// 2-4 KB -> L1-resident across the 3 tap reads). Only the d1->d2 intermediate
// (Rs) lives in LDS. Negative-t taps masked to zero (causal pad).
//   out[co][t] = sum_{ci,jt} W[co][jt*CIeff+ci] * X[ci][t - DIL*jt]
// ---------------------------------------------------------------------------
template <int CI, int DIL>
__global__ __launch_bounds__(64) void d12m_kernel(
    const unsigned short* __restrict__ Hin,  // [Bc][N][T][CI] bf16
    const unsigned short* __restrict__ apk,  // stage base: d1 sets, then d2
    unsigned short* __restrict__ out) {      // [Bc][N][T][16] bf16
  constexpr int HALO = 8;
  __shared__ __align__(16) unsigned short Rs[HALO + T][16];
  const int l = threadIdx.x;
  const int tcol = l & 15, q = l >> 4;
  const int n = swz_n(blockIdx.x), by = blockIdx.y;

  // zero Rs halo (causal zero-pad; d2's tap reach 2*DIL <= 8)
  if (l < 16) {
    *(u8v*)&Rs[l >> 1][(l & 1) * 8] = (u8v)0;
  }

  // A fragments (prepacked; pad region zeros so B garbage is harmless)
  s8v a1_0, a1_1, a2_0, a2_1;
  constexpr int ND1 = (CI == 8) ? 1 : 2;
  a1_0 = *(const s8v*)&apk[(0 * 64 + l) * 8];
  if constexpr (CI == 16) a1_1 = *(const s8v*)&apk[(1 * 64 + l) * 8];
  a2_0 = *(const s8v*)&apk[((ND1 + 0) * 64 + l) * 8];
  a2_1 = *(const s8v*)&apk[((ND1 + 1) * 64 + l) * 8];

  const unsigned short* Hb = Hin + ((size_t)by * N + n) * T * CI;
  __syncthreads();  // Rs halo visible

  // ---- d1: 8 t-tiles, B direct from global ----
#pragma unroll 2
  for (int tt = 0; tt < 8; tt++) {
    const int t = tt * 16 + tcol;
    f4v acc = (f4v)0.f;
    if constexpr (CI == 8) {
      // K=24 in one MFMA (k = jt*8+ci); q==3 is A-zero pad
      const int jt = (q < 3) ? q : 2;
      const int idx = t - DIL * jt;
      s8v bf = *(const s8v*)&Hb[(size_t)(idx < 0 ? 0 : idx) * 8];
      if (idx < 0) bf = (s8v){0, 0, 0, 0, 0, 0, 0, 0};
      acc = __builtin_amdgcn_mfma_f32_16x16x32_bf16(a1_0, bf, acc, 0, 0, 0);
    } else {
      {
        const int jt = q >> 1, ci0 = (q & 1) * 8;
        const int idx = t - DIL * jt;
        s8v bf = *(const s8v*)&Hb[(size_t)(idx < 0 ? 0 : idx) * 16 + ci0];
        if (idx < 0) bf = (s8v){0, 0, 0, 0, 0, 0, 0, 0};
        acc = __builtin_amdgcn_mfma_f32_16x16x32_bf16(a1_0, bf, acc, 0, 0, 0);
      }
      {
        const int ci0 = (q & 1) * 8;  // jt=2 for q<2; A-zero pad for q>=2
        const int idx = t - DIL * 2;
        s8v bf = *(const s8v*)&Hb[(size_t)(idx < 0 ? 0 : idx) * 16 + ci0];
        if (idx < 0) bf = (s8v){0, 0, 0, 0, 0, 0, 0, 0};
        acc = __builtin_amdgcn_mfma_f32_16x16x32_bf16(a1_1, bf, acc, 0, 0, 0);
      }
    }
    u4s rb;
#pragma unroll
    for (int r = 0; r < 4; r++) rb[r] = f2bf(fmaxf(acc[r], 0.f));
    *(u4s*)&Rs[HALO + t][q * 4] = rb;
  }
  __syncthreads();

  // ---- d2: 8 t-tiles (K=48, k = jt*16+cm), B from Rs ----
  unsigned short* opb = &out[((size_t)by * N + n) * T * 16];
#pragma unroll 2
  for (int tt = 0; tt < 8; tt++) {
    const int t = tt * 16 + tcol;
    f4v acc = (f4v)0.f;
    {
      const int jt = q >> 1, ci0 = (q & 1) * 8;
      s8v bf = *(const s8v*)&Rs[HALO + t - DIL * jt][ci0];
      acc = __builtin_amdgcn_mfma_f32_16x16x32_bf16(a2_0, bf, acc, 0, 0, 0);
    }
    {
      const int ci0 = (q & 1) * 8;  // jt=2 for q<2; A-zero pad otherwise
      s8v bf = *(const s8v*)&Rs[HALO + t - DIL * 2][ci0];
      acc = __builtin_amdgcn_mfma_f32_16x16x32_bf16(a2_1, bf, acc, 0, 0, 0);
    }
    u4s ob;
#pragma unroll
    for (int r = 0; r < 4; r++) ob[r] = f2bf(fmaxf(acc[r], 0.f));
    *(u4s*)&opb[(size_t)t * 16 + q * 4] = ob;
  }
}

// ---------------------------------------------------------------------------
// K3/K5/K7: cross-stock 11x1 conv via MFMA. All H tensors now bf16
// channel-interleaved [Bc][N][T][C]; output likewise (u4s store).
// RESMODE: 0 = x-proj+rw (fp32 x), 1 = rw @ bf16 H, 2 = identity bf16 H.
// ---------------------------------------------------------------------------
template <int C, int CIR, int RESMODE>
__global__ __launch_bounds__(64) void ccm_kernel(
    const unsigned short* __restrict__ zin,  // [Bc][N][T][C] bf16
    const unsigned short* __restrict__ apk,  // [NMF][64][8] bf16
    const void* __restrict__ resin,          // RESMODE 0: fp32 x; else bf16
    const float* __restrict__ rw,
    const float* __restrict__ pw, const float* __restrict__ pb,
    unsigned short* __restrict__ out,        // [Bc][N][T][C] bf16
    int b0) {
  constexpr int NMF = (C == 8) ? 3 : 6;
  const int L = threadIdx.x;
  const int tcol = L & 15, q = L >> 4;
  const int n = swz_n(blockIdx.x);
  const int t = blockIdx.y * 16 + tcol;
  const int by = blockIdx.z;
  const int b = b0 + by;

  f4v d = {0.f, 0.f, 0.f, 0.f};
#pragma unroll
  for (int p = 0; p < NMF; p++) {
    int dn = (C == 8) ? (p * 4 + q) : (p * 2 + (q >> 1));
    int row = n + dn - 5;
    bool ok = (unsigned)row < (unsigned)N;
    int rowc = ok ? row : 0;
    const unsigned short* bp =
        &zin[(((size_t)by * N + rowc) * T + t) * C + ((C == 16) ? (q & 1) * 8 : 0)];
    s8v bfrag = *(const s8v*)bp;
    if (!ok) bfrag = (s8v){0, 0, 0, 0, 0, 0, 0, 0};
    s8v afrag = *(const s8v*)&apk[(p * 64 + L) * 8];
    d = __builtin_amdgcn_mfma_f32_16x16x32_bf16(afrag, bfrag, d, 0, 0, 0);
  }

  if (C == 8 && q >= 2) return;

  float y[4];
  if constexpr (RESMODE == 0) {
    float4 xr = ((const float4*)resin)[((size_t)b * N + n) * T + t];
    float xv[4];
#pragma unroll
    for (int j = 0; j < 4; j++)
      xv[j] = pb[j] + pw[j * 4 + 0] * xr.x + pw[j * 4 + 1] * xr.y +
              pw[j * 4 + 2] * xr.z + pw[j * 4 + 3] * xr.w;
#pragma unroll
    for (int r = 0; r < 4; r++) {
      int co = q * 4 + r;
      float rv = rw[co * 4 + 0] * xv[0] + rw[co * 4 + 1] * xv[1] +
                 rw[co * 4 + 2] * xv[2] + rw[co * 4 + 3] * xv[3];
      y[r] = fmaxf(rv + fmaxf(d[r], 0.f), 0.f);
    }
  } else if constexpr (RESMODE == 1) {
    const unsigned short* hp =
        (const unsigned short*)resin + (((size_t)by * N + n) * T + t) * CIR;
    u8v hb = *(const u8v*)hp;  // CIR == 8
    float hv[8];
#pragma unroll
    for (int ci = 0; ci < 8; ci++) hv[ci] = bf2f(hb[ci]);
#pragma unroll
    for (int r = 0; r < 4; r++) {
      int co = q * 4 + r;
      float rv = 0.f;
#pragma unroll
      for (int ci = 0; ci < 8; ci++) rv += rw[co * 8 + ci] * hv[ci];
      y[r] = fmaxf(rv + fmaxf(d[r], 0.f), 0.f);
    }
  } else {
    const unsigned short* hp =
        (const unsigned short*)resin + (((size_t)by * N + n) * T + t) * 16 + q * 4;
    u4s hb = *(const u4s*)hp;
#pragma unroll
    for (int r = 0; r < 4; r++)
      y[r] = fmaxf(bf2f(hb[r]) + fmaxf(d[r], 0.f), 0.f);
  }
  u4s ov;
#pragma unroll
  for (int r = 0; r < 4; r++) ov[r] = f2bf(y[r]);
  *(u4s*)&out[(((size_t)by * N + n) * T + t) * C + q * 4] = ov;
}

// ---------------------------------------------------------------------------
// conv4: h4[b][o][n] = relu(sum_{ci,t} w4[o][ci][t] * Y[ci][t]).
// One 64-lane wave per (b,n); Y bf16 interleaved [Bc][N][T][16].
// ---------------------------------------------------------------------------
__global__ __launch_bounds__(64) void conv4_kernel(
    const unsigned short* __restrict__ Y,  // [Bc][N][T][16] bf16
    const float* __restrict__ w4,          // [16][16][T]
    float* __restrict__ h4,                // [B][16][N]
    int b0) {
  const int tl = threadIdx.x;
  const int n = swz_n(blockIdx.x), by = blockIdx.y;
  const int b = b0 + by;
  const int t0 = tl * 2;

  const unsigned short* yp = Y + (((size_t)by * N + n) * T + t0) * 16;
  u8v r0a = *(const u8v*)&yp[0];
  u8v r0b = *(const u8v*)&yp[8];
  u8v r1a = *(const u8v*)&yp[16];
  u8v r1b = *(const u8v*)&yp[24];
  vf2 y[16];
#pragma unroll
  for (int ci = 0; ci < 8; ci++) {
    y[ci] = (vf2){bf2f(r0a[ci]), bf2f(r1a[ci])};
    y[8 + ci] = (vf2){bf2f(r0b[ci]), bf2f(r1b[ci])};
  }

#pragma unroll 1
  for (int o = 0; o < 16; o++) {
    vf2 s = (vf2)0.f;
#pragma unroll
    for (int ci = 0; ci < 16; ci++) {
      vf2 w = *(const vf2*)&w4[(size_t)(o * 16 + ci) * T + t0];
      s += w * y[ci];
    }
    float sum = s.x + s.y;
    sum += __shfl_down(sum, 32);
    sum += __shfl_down(sum, 16);
    sum += __shfl_down(sum, 8);
    sum += __shfl_down(sum, 4);
    sum += __shfl_down(sum, 2);
    sum += __shfl_down(sum, 1);
    if (tl == 0) h4[((size_t)b * 16 + o) * N + n] = fmaxf(sum, 0.f);
  }
}

// ---------------------------------------------------------------------------
// K8: logits (torch reshape scramble) + softmax over N
// ---------------------------------------------------------------------------
__global__ __launch_bounds__(128) void final_kernel(
    const float* __restrict__ hl, const float* __restrict__ h4,
    const float* __restrict__ ow, const float* __restrict__ ob,
    float* __restrict__ out) {
  __shared__ float red[128];
  int b = blockIdx.x, n = threadIdx.x;
  bool valid = n < N;
  float lv = 0.f;
  if (valid) {
    int idx = b * N + n;
    int sb = idx & (B - 1);
    int sn = idx >> 8;
    const float* h = &hl[((size_t)sb * N + sn) * 16];
    float a = ob[0];
#pragma unroll
    for (int k = 0; k < 16; k++) a += h[k] * ow[k];
#pragma unroll
    for (int c = 0; c < 16; c++) a += h4[((size_t)b * 16 + c) * N + n] * ow[16 + c];
    lv = a;
  }
  red[n] = valid ? lv : -1e30f;
  __syncthreads();
  for (int off = 64; off > 0; off >>= 1) {
    if (n < off) red[n] = fmaxf(red[n], red[n + off]);
    __syncthreads();
  }
  float m = red[0];
  __syncthreads();
  float e = valid ? __expf(lv - m) : 0.f;
  red[n] = e;
  __syncthreads();
  for (int off = 64; off > 0; off >>= 1) {
    if (n < off) red[n] += red[n + off];
    __syncthreads();
  }
  float s = red[0];
  if (valid) out[(size_t)b * N + n] = e / s;
}

// ---------------------------------------------------------------------------
// Launch. Chunked over B. Everything between stages is now bf16 interleaved
// [Bc][N][T][C]. Per-b unit: Zb1(8ch=4) + H1(8ch=4) + Zb2(16ch=8) +
// H2(16ch=8) + Y3(16ch=8) = 32 NT-floats (was 52).
// ---------------------------------------------------------------------------
extern "C" void kernel_launch(void* const* d_in, const int* in_sizes, int n_in,
                              void* d_out, int out_size, void* d_ws, size_t ws_size,
                              hipStream_t stream) {
  const float* x    = (const float*)d_in[0];
  const float* pw   = (const float*)d_in[1];
  const float* pb   = (const float*)d_in[2];
  const float* w_ih = (const float*)d_in[3];
  const float* w_hh = (const float*)d_in[4];
  const float* b_ih = (const float*)d_in[5];
  const float* b_hh = (const float*)d_in[6];
  const float* t1d1 = (const float*)d_in[7];
  const float* t1d2 = (const float*)d_in[8];
  const float* t1c  = (const float*)d_in[9];
  const float* t1r  = (const float*)d_in[10];
  const float* t2d1 = (const float*)d_in[11];
  const float* t2d2 = (const float*)d_in[12];
  const float* t2c  = (const float*)d_in[13];
  const float* t2r  = (const float*)d_in[14];
  const float* t3d1 = (const float*)d_in[15];
  const float* t3d2 = (const float*)d_in[16];
  const float* t3c  = (const float*)d_in[17];
  const float* w4   = (const float*)d_in[18];
  const float* ow   = (const float*)d_in[19];
  const float* ob   = (const float*)d_in[20];
  float* outp = (float*)d_out;

  const size_t NT = (size_t)N * T;            // 12928
  const size_t Bn16 = (size_t)B * N * 16;
  const size_t unit = 32 * NT;                // floats per chunked b
  const size_t fixed = 2 * Bn16 + 8192;       // hl + h4 + apk

  int Bc = 4;
  const int cands[7] = {256, 128, 64, 32, 16, 8, 4};
  for (int i = 0; i < 7; i++) {
    if ((cands[i] * unit + fixed) * sizeof(float) <= ws_size) { Bc = cands[i]; break; }
  }

  float* ws = (float*)d_ws;
  float* hl = ws;                              // [B*N][16]
  float* h4 = hl + Bn16;                       // [B][16][N]
  unsigned short* apk = (unsigned short*)(h4 + Bn16);  // 22*512 ushorts
  float* p = h4 + Bn16 + 8192;
  unsigned short* Zb1 = (unsigned short*)p; p += (size_t)Bc * 4 * NT;
  unsigned short* H1b = (unsigned short*)p; p += (size_t)Bc * 4 * NT;
  unsigned short* Zb2 = (unsigned short*)p; p += (size_t)Bc * 8 * NT;
  unsigned short* H2b = (unsigned short*)p; p += (size_t)Bc * 8 * NT;
  unsigned short* Y3b = (unsigned short*)p;

  prep_kernel<<<1, 64, 0, stream>>>(t1c, t2c, t3c, t2d1, t2d2, t3d1, t3d2, apk);
  lstm_kernel<<<(B * N) / 8, 64, 0, stream>>>(x, pw, pb, w_ih, w_hh, b_ih,
                                              b_hh, hl);

  dim3 g(N, Bc);
  dim3 gm(N, T / 16, Bc);
  for (int b0 = 0; b0 < B; b0 += Bc) {
    d12a_kernel<<<g, 128, 0, stream>>>(x, pw, pb, t1d1, t1d2, Zb1, b0);
    ccm_kernel<8, 4, 0><<<gm, 64, 0, stream>>>(
        Zb1, apk + 0 * 512, x, t1r, pw, pb, H1b, b0);

    d12m_kernel<8, 2><<<g, 64, 0, stream>>>(H1b, apk + 15 * 512, Zb2);
    ccm_kernel<16, 8, 1><<<gm, 64, 0, stream>>>(
        Zb2, apk + 3 * 512, H1b, t2r, pw, pb, H2b, b0);

    d12m_kernel<16, 4><<<g, 64, 0, stream>>>(H2b, apk + 18 * 512, Zb2);
    ccm_kernel<16, 16, 2><<<gm, 64, 0, stream>>>(
        Zb2, apk + 9 * 512, H2b, nullptr, pw, pb, Y3b, b0);

    conv4_kernel<<<g, 64, 0, stream>>>(Y3b, w4, h4, b0);
  }

  final_kernel<<<B, 128, 0, stream>>>(hl, h4, ow, ob, outp);
}

// Round 6
// 803.125 us; speedup vs baseline: 2.7539x; 1.1659x over previous
//
#include <hip/hip_runtime.h>
#include <hip/hip_bf16.h>

// ---------------------------------------------------------------------------
// Problem constants (reference: B,N,T,P,H = 256,101,128,4,16)
// ---------------------------------------------------------------------------
constexpr int B = 256;
constexpr int N = 101;
constexpr int T = 128;

typedef float vf2 __attribute__((ext_vector_type(2)));
typedef short s8v __attribute__((ext_vector_type(8)));    // 8 bf16 (4 VGPRs)
typedef unsigned short u8v __attribute__((ext_vector_type(8)));
typedef unsigned short u4s __attribute__((ext_vector_type(4)));
typedef float f4v __attribute__((ext_vector_type(4)));    // MFMA accum

__device__ __forceinline__ float frcp(float x) { return __builtin_amdgcn_rcpf(x); }
__device__ __forceinline__ float sigmoidf_(float x) { return frcp(1.f + __expf(-x)); }
__device__ __forceinline__ float tanhf_(float x) { return 2.f * frcp(1.f + __expf(-2.f * x)) - 1.f; }

// fp32 -> bf16 bits, round-nearest-even
__device__ __forceinline__ unsigned short f2bf(float x) {
  unsigned int u = __float_as_uint(x);
  u = (u + 0x7FFFu + ((u >> 16) & 1u)) >> 16;
  return (unsigned short)u;
}
// bf16 bits -> fp32
__device__ __forceinline__ float bf2f(unsigned short u) {
  return __uint_as_float((unsigned int)u << 16);
}

// XCD-aware n-swizzle. Bijection on [0,101).
__device__ __forceinline__ int swz_n(int L) {
  int q = L & 7, r = L >> 3;
  return q * 13 - (q > 5 ? (q - 5) : 0) + r;
}

// ---------------------------------------------------------------------------
// K1: LSTM. R0 structure + proj fold (measured ~205 us; best of 3 variants).
// 8 seqs/wave (sub=lane>>4 owns a vf2 seq-pair), h via per-sub LDS row.
// ---------------------------------------------------------------------------
__global__ __launch_bounds__(64) void lstm_kernel(
    const float* __restrict__ x, const float* __restrict__ pw,
    const float* __restrict__ pb, const float* __restrict__ w_ih,
    const float* __restrict__ w_hh, const float* __restrict__ b_ih,
    const float* __restrict__ b_hh, float* __restrict__ h_out) {
  __shared__ vf2 sh[4][16];  // [sub][unit] -> (rowA, rowB)
  const int lane = threadIdx.x;
  const int sub = lane >> 4;
  const int k = lane & 15;
  const int row = blockIdx.x * 8 + sub * 2;  // 3232*8 = 25856

  float wf[4][4], whh[4][16], bias[4];
#pragma unroll
  for (int q = 0; q < 4; q++) {
    const int j = q * 16 + k;  // gate order i,f,g,o
    float bp = b_ih[j] + b_hh[j];
#pragma unroll
    for (int c = 0; c < 4; c++) bp += w_ih[j * 4 + c] * pb[c];
    bias[q] = bp;
#pragma unroll
    for (int p = 0; p < 4; p++) {
      float s = 0.f;
#pragma unroll
      for (int c = 0; c < 4; c++) s += w_ih[j * 4 + c] * pw[c * 4 + p];
      wf[q][p] = s;
    }
#pragma unroll
    for (int m = 0; m < 16; m++) whh[q][m] = w_hh[j * 16 + m];
  }

  vf2 h = {0.f, 0.f}, c = {0.f, 0.f};
  sh[sub][k] = h;
  const float4* xpA = (const float4*)x + (size_t)row * T;
  const float4* xpB = xpA + T;

#pragma unroll 1
  for (int t = 0; t < T; t++) {
    __syncthreads();
    float4 xa = xpA[t];
    float4 xb = xpB[t];
    vf2 xc0 = {xa.x, xb.x}, xc1 = {xa.y, xb.y};
    vf2 xc2 = {xa.z, xb.z}, xc3 = {xa.w, xb.w};
    vf2 a0 = {bias[0], bias[0]}, a1 = {bias[1], bias[1]};
    vf2 a2 = {bias[2], bias[2]}, a3 = {bias[3], bias[3]};
    a0 += wf[0][0] * xc0 + wf[0][1] * xc1 + wf[0][2] * xc2 + wf[0][3] * xc3;
    a1 += wf[1][0] * xc0 + wf[1][1] * xc1 + wf[1][2] * xc2 + wf[1][3] * xc3;
    a2 += wf[2][0] * xc0 + wf[2][1] * xc1 + wf[2][2] * xc2 + wf[2][3] * xc3;
    a3 += wf[3][0] * xc0 + wf[3][1] * xc1 + wf[3][2] * xc2 + wf[3][3] * xc3;
#pragma unroll
    for (int mm = 0; mm < 4; mm++) {
      vf2 hm0 = sh[sub][mm * 4 + 0];
      vf2 hm1 = sh[sub][mm * 4 + 1];
      vf2 hm2 = sh[sub][mm * 4 + 2];
      vf2 hm3 = sh[sub][mm * 4 + 3];
      a0 += whh[0][mm * 4 + 0] * hm0 + whh[0][mm * 4 + 1] * hm1 +
            whh[0][mm * 4 + 2] * hm2 + whh[0][mm * 4 + 3] * hm3;
      a1 += whh[1][mm * 4 + 0] * hm0 + whh[1][mm * 4 + 1] * hm1 +
            whh[1][mm * 4 + 2] * hm2 + whh[1][mm * 4 + 3] * hm3;
      a2 += whh[2][mm * 4 + 0] * hm0 + whh[2][mm * 4 + 1] * hm1 +
            whh[2][mm * 4 + 2] * hm2 + whh[2][mm * 4 + 3] * hm3;
      a3 += whh[3][mm * 4 + 0] * hm0 + whh[3][mm * 4 + 1] * hm1 +
            whh[3][mm * 4 + 2] * hm2 + whh[3][mm * 4 + 3] * hm3;
    }
    vf2 ig, fg, gg, og, tc;
    ig.x = sigmoidf_(a0.x); ig.y = sigmoidf_(a0.y);
    fg.x = sigmoidf_(a1.x); fg.y = sigmoidf_(a1.y);
    gg.x = tanhf_(a2.x);    gg.y = tanhf_(a2.y);
    og.x = sigmoidf_(a3.x); og.y = sigmoidf_(a3.y);
    c = fg * c + ig * gg;
    tc.x = tanhf_(c.x);     tc.y = tanhf_(c.y);
    h = og * tc;
    __syncthreads();
    sh[sub][k] = h;
  }
  h_out[(size_t)row * 16 + k] = h.x;
  h_out[(size_t)(row + 1) * 16 + k] = h.y;
}

// ---------------------------------------------------------------------------
// Prep: pack conv weights into MFMA A-fragment order (bf16).
// Sets 0..14: cc convs. Sets 15..21: d1/d2 of stages 2/3 (K=jt*CIeff+ci,
// zero-padded past K=3*CIeff so the B pad region needs no masking):
//   15: s2 d1 (CIw=8)   16,17: s2 d2   18,19: s3 d1   20,21: s3 d2
// ---------------------------------------------------------------------------
__global__ void prep_kernel(const float* __restrict__ t1c,
                            const float* __restrict__ t2c,
                            const float* __restrict__ t3c,
                            const float* __restrict__ t2d1,
                            const float* __restrict__ t2d2,
                            const float* __restrict__ t3d1,
                            const float* __restrict__ t3d2,
                            unsigned short* __restrict__ apk) {
  const int L = threadIdx.x;  // 64 threads
  const int co = L & 15, q = L >> 4;
#pragma unroll 1
  for (int set = 0; set < 15; set++) {
    int s, p;
    if (set < 3) { s = 0; p = set; }
    else if (set < 9) { s = 1; p = set - 3; }
    else { s = 2; p = set - 9; }
    u8v f;
#pragma unroll
    for (int j = 0; j < 8; j++) {
      float val = 0.f;
      if (s == 0) {
        int dn = p * 4 + q, ci = j;
        if (co < 8 && dn < 11) val = t1c[(co * 8 + ci) * 11 + dn];
      } else {
        int dn = p * 2 + (q >> 1), ci = (q & 1) * 8 + j;
        const float* w = (s == 1) ? t2c : t3c;
        if (dn < 11) val = w[(co * 16 + ci) * 11 + dn];
      }
      f[j] = f2bf(val);
    }
    *(u8v*)&apk[(set * 64 + L) * 8] = f;
  }
#pragma unroll 1
  for (int ds = 0; ds < 7; ds++) {
    const float* w; int CIw, CIeff, kk;
    switch (ds) {
      case 0: w = t2d1; CIw = 8;  CIeff = 8;  kk = 0; break;
      case 1: w = t2d2; CIw = 16; CIeff = 16; kk = 0; break;
      case 2: w = t2d2; CIw = 16; CIeff = 16; kk = 1; break;
      case 3: w = t3d1; CIw = 16; CIeff = 16; kk = 0; break;
      case 4: w = t3d1; CIw = 16; CIeff = 16; kk = 1; break;
      case 5: w = t3d2; CIw = 16; CIeff = 16; kk = 0; break;
      default: w = t3d2; CIw = 16; CIeff = 16; kk = 1; break;
    }
    u8v f;
#pragma unroll
    for (int j = 0; j < 8; j++) {
      int kg = kk * 32 + q * 8 + j;
      int ci = kg % CIeff, jt = kg / CIeff;
      float val = (jt < 3) ? w[(co * CIw + ci) * 3 + jt] : 0.f;
      f[j] = f2bf(val);
    }
    *(u8v*)&apk[((15 + ds) * 64 + L) * 8] = f;
  }
}

// ---------------------------------------------------------------------------
// K2 (stage 1 only): fused d1+d2, proj folded, fp32 x input, bf16
// channel-interleaved output [by][n][t][8].
// ---------------------------------------------------------------------------
__global__ __launch_bounds__(128) void d12a_kernel(
    const float* __restrict__ xin,
    const float* __restrict__ pw, const float* __restrict__ pb,
    const float* __restrict__ w1,  // [8][4][3]
    const float* __restrict__ w2,  // [8][8][3]
    unsigned short* __restrict__ out, int b0) {
  constexpr int CI = 4, CO = 8, DIL = 1;
  const int t = threadIdx.x;
  const int n = swz_n(blockIdx.x), by = blockIdx.y;
  const int b = b0 + by;

  float r1[3][CO];
#pragma unroll
  for (int u = 0; u < 3; u++)
#pragma unroll
    for (int co = 0; co < CO; co++) r1[u][co] = 0.f;

  const float4* xp = (const float4*)xin + ((size_t)b * N + n) * T;
  float px[5][4];
#pragma unroll
  for (int v = 0; v < 5; v++) {
    int idx = t - v * DIL;
    float4 xr = xp[idx < 0 ? 0 : idx];
    bool ok = idx >= 0;
    px[v][0] = ok ? pb[0] + pw[0] * xr.x + pw[1] * xr.y + pw[2] * xr.z + pw[3] * xr.w : 0.f;
    px[v][1] = ok ? pb[1] + pw[4] * xr.x + pw[5] * xr.y + pw[6] * xr.z + pw[7] * xr.w : 0.f;
    px[v][2] = ok ? pb[2] + pw[8] * xr.x + pw[9] * xr.y + pw[10] * xr.z + pw[11] * xr.w : 0.f;
    px[v][3] = ok ? pb[3] + pw[12] * xr.x + pw[13] * xr.y + pw[14] * xr.z + pw[15] * xr.w : 0.f;
  }
#pragma unroll
  for (int ci = 0; ci < CI; ci++) {
#pragma unroll
    for (int j = 0; j < 3; j++) {
#pragma unroll
      for (int co = 0; co < CO; co++) {
        float w = w1[(co * CI + ci) * 3 + j];
#pragma unroll
        for (int u = 0; u < 3; u++) r1[u][co] += w * px[u + 2 - j][ci];
      }
    }
  }
#pragma unroll
  for (int u = 0; u < 3; u++)
#pragma unroll
    for (int co = 0; co < CO; co++) r1[u][co] = fmaxf(r1[u][co], 0.f);

  float acc[CO];
#pragma unroll
  for (int co = 0; co < CO; co++) acc[co] = 0.f;
#pragma unroll
  for (int cm = 0; cm < CO; cm++) {
#pragma unroll
    for (int j = 0; j < 3; j++) {
#pragma unroll
      for (int co = 0; co < CO; co++)
        acc[co] += w2[(co * CO + cm) * 3 + j] * r1[2 - j][cm];
    }
  }
  unsigned short* op = &out[(((size_t)by * N + n) * T + t) * CO];
  u8v a;
#pragma unroll
  for (int j = 0; j < 8; j++) a[j] = f2bf(fmaxf(acc[j], 0.f));
  *(u8v*)&op[0] = a;
}

// ---------------------------------------------------------------------------
// cd2: FUSED ccm (cross-stock 11x1 via MFMA, +residual) -> H, then the next
// stage's d1+d2 (dilated convs via MFMA) -> z. H passes through LDS (n-local
// edge); H also goes to global for the NEXT ccm's residual. One wave per
// (n,by), 8 internal t-tiles per phase.
//   C==8 : ccm t1 (NMF=3, x-proj residual), d12 stage2 (CI=8,  DIL=2)
//   C==16: ccm t2 (NMF=6, rw@H1 residual),  d12 stage3 (CI=16, DIL=4)
// ---------------------------------------------------------------------------
template <int C, int DIL>
__global__ __launch_bounds__(64) void cd2_kernel(
    const unsigned short* __restrict__ zin,   // [Bc][N][T][C] bf16
    const unsigned short* __restrict__ apkc,  // ccm A-frags [NMF][64][8]
    const unsigned short* __restrict__ apkd,  // d12 A-frags (d1 then d2)
    const void* __restrict__ resin,           // C==8: fp32 x; C==16: bf16 H1
    const float* __restrict__ rw,
    const float* __restrict__ pw, const float* __restrict__ pb,
    unsigned short* __restrict__ hout,        // [Bc][N][T][C] bf16
    unsigned short* __restrict__ zout,        // [Bc][N][T][16] bf16
    int b0) {
  constexpr int NMF = (C == 8) ? 3 : 6;
  constexpr int HALO = 8;
  __shared__ __align__(16) unsigned short Hs[HALO + T][C];
  __shared__ __align__(16) unsigned short Rs[HALO + T][16];
  const int l = threadIdx.x;
  const int tcol = l & 15, q = l >> 4;
  const int n = swz_n(blockIdx.x);
  const int by = blockIdx.y;
  const int b = b0 + by;

  // zero halos (causal zero-pad; tap reach 2*DIL <= 8)
  if (l < 16) {
    *(u8v*)&Rs[l >> 1][(l & 1) * 8] = (u8v)0;
    if constexpr (C == 8) {
      if (l < 8) *(u8v*)&Hs[l][0] = (u8v)0;
    } else {
      *(u8v*)&Hs[l >> 1][(l & 1) * 8] = (u8v)0;
    }
  }

  // A fragments
  s8v ac[NMF];
#pragma unroll
  for (int p = 0; p < NMF; p++) ac[p] = *(const s8v*)&apkc[(p * 64 + l) * 8];
  constexpr int ND1 = (C == 8) ? 1 : 2;
  s8v a1_0 = *(const s8v*)&apkd[(0 * 64 + l) * 8];
  s8v a1_1 = a1_0;
  if constexpr (C == 16) a1_1 = *(const s8v*)&apkd[(1 * 64 + l) * 8];
  s8v a2_0 = *(const s8v*)&apkd[((ND1 + 0) * 64 + l) * 8];
  s8v a2_1 = *(const s8v*)&apkd[((ND1 + 1) * 64 + l) * 8];

  // ---- phase 1: ccm + residual -> H (global + LDS) ----
#pragma unroll 1
  for (int tt = 0; tt < 8; tt++) {
    const int t = tt * 16 + tcol;
    f4v d = (f4v)0.f;
#pragma unroll
    for (int p = 0; p < NMF; p++) {
      int dn = (C == 8) ? (p * 4 + q) : (p * 2 + (q >> 1));
      int row = n + dn - 5;
      bool ok = (unsigned)row < (unsigned)N;
      int rowc = ok ? row : 0;
      const unsigned short* bp =
          &zin[(((size_t)by * N + rowc) * T + t) * C + ((C == 16) ? (q & 1) * 8 : 0)];
      s8v bfrag = *(const s8v*)bp;
      if (!ok) bfrag = (s8v){0, 0, 0, 0, 0, 0, 0, 0};
      d = __builtin_amdgcn_mfma_f32_16x16x32_bf16(ac[p], bfrag, d, 0, 0, 0);
    }
    if constexpr (C == 8) {
      if (q < 2) {
        float4 xr = ((const float4*)resin)[((size_t)b * N + n) * T + t];
        float xv[4];
#pragma unroll
        for (int j = 0; j < 4; j++)
          xv[j] = pb[j] + pw[j * 4 + 0] * xr.x + pw[j * 4 + 1] * xr.y +
                  pw[j * 4 + 2] * xr.z + pw[j * 4 + 3] * xr.w;
        u4s hb16;
#pragma unroll
        for (int r = 0; r < 4; r++) {
          int co = q * 4 + r;
          float rv = rw[co * 4 + 0] * xv[0] + rw[co * 4 + 1] * xv[1] +
                     rw[co * 4 + 2] * xv[2] + rw[co * 4 + 3] * xv[3];
          hb16[r] = f2bf(fmaxf(rv + fmaxf(d[r], 0.f), 0.f));
        }
        *(u4s*)&hout[(((size_t)by * N + n) * T + t) * 8 + q * 4] = hb16;
        *(u4s*)&Hs[HALO + t][q * 4] = hb16;
      }
    } else {
      const unsigned short* hp =
          (const unsigned short*)resin + (((size_t)by * N + n) * T + t) * 8;
      u8v hb = *(const u8v*)hp;  // H1: 8 channels
      float hv[8];
#pragma unroll
      for (int ci = 0; ci < 8; ci++) hv[ci] = bf2f(hb[ci]);
      u4s hb16;
#pragma unroll
      for (int r = 0; r < 4; r++) {
        int co = q * 4 + r;
        float rv = 0.f;
#pragma unroll
        for (int ci = 0; ci < 8; ci++) rv += rw[co * 8 + ci] * hv[ci];
        hb16[r] = f2bf(fmaxf(rv + fmaxf(d[r], 0.f), 0.f));
      }
      *(u4s*)&hout[(((size_t)by * N + n) * T + t) * 16 + q * 4] = hb16;
      *(u4s*)&Hs[HALO + t][q * 4] = hb16;
    }
  }
  __syncthreads();

  // ---- phase 2: d1 from Hs -> Rs ----
#pragma unroll 2
  for (int tt = 0; tt < 8; tt++) {
    const int t = tt * 16 + tcol;
    f4v acc = (f4v)0.f;
    if constexpr (C == 8) {
      const int jt = (q < 3) ? q : 2;  // q==3 is A-zero pad
      s8v bf = *(const s8v*)&Hs[HALO + t - DIL * jt][0];
      acc = __builtin_amdgcn_mfma_f32_16x16x32_bf16(a1_0, bf, acc, 0, 0, 0);
    } else {
      {
        const int jt = q >> 1, ci0 = (q & 1) * 8;
        s8v bf = *(const s8v*)&Hs[HALO + t - DIL * jt][ci0];
        acc = __builtin_amdgcn_mfma_f32_16x16x32_bf16(a1_0, bf, acc, 0, 0, 0);
      }
      {
        const int ci0 = (q & 1) * 8;  // jt=2 for q<2; A-zero pad otherwise
        s8v bf = *(const s8v*)&Hs[HALO + t - DIL * 2][ci0];
        acc = __builtin_amdgcn_mfma_f32_16x16x32_bf16(a1_1, bf, acc, 0, 0, 0);
      }
    }
    u4s rb;
#pragma unroll
    for (int r = 0; r < 4; r++) rb[r] = f2bf(fmaxf(acc[r], 0.f));
    *(u4s*)&Rs[HALO + t][q * 4] = rb;
  }
  __syncthreads();

  // ---- phase 3: d2 from Rs -> zout ----
  unsigned short* opb = &zout[((size_t)by * N + n) * T * 16];
#pragma unroll 2
  for (int tt = 0; tt < 8; tt++) {
    const int t = tt * 16 + tcol;
    f4v acc = (f4v)0.f;
    {
      const int jt = q >> 1, ci0 = (q & 1) * 8;
      s8v bf = *(const s8v*)&Rs[HALO + t - DIL * jt][ci0];
      acc = __builtin_amdgcn_mfma_f32_16x16x32_bf16(a2_0, bf, acc, 0, 0, 0);
    }
    {
      const int ci0 = (q & 1) * 8;
      s8v bf = *(const s8v*)&Rs[HALO + t - DIL * 2][ci0];
      acc = __builtin_amdgcn_mfma_f32_16x16x32_bf16(a2_1, bf, acc, 0, 0, 0);
    }
    u4s ob;
#pragma unroll
    for (int r = 0; r < 4; r++) ob[r] = f2bf(fmaxf(acc[r], 0.f));
    *(u4s*)&opb[(size_t)t * 16 + q * 4] = ob;
  }
}

// ---------------------------------------------------------------------------
// cy: FUSED ccm t3 (identity residual) -> Y (fp32, LDS ONLY — never global)
// -> conv4 reduction -> h4. One wave per (n,by).
// ---------------------------------------------------------------------------
__global__ __launch_bounds__(64) void cy_kernel(
    const unsigned short* __restrict__ zin,   // Zb2b [Bc][N][T][16] bf16
    const unsigned short* __restrict__ apkc,  // sets 9..14
    const unsigned short* __restrict__ resin, // H2 [Bc][N][T][16] bf16
    const float* __restrict__ w4,             // [16][16][T]
    float* __restrict__ h4,                   // [B][16][N]
    int b0) {
  __shared__ __align__(16) float Ys[16][T + 2];  // [ci][t], stride 130 (8B-aligned rows, conflict-free vf2)
  const int l = threadIdx.x;
  const int tcol = l & 15, q = l >> 4;
  const int n = swz_n(blockIdx.x);
  const int by = blockIdx.y;
  const int b = b0 + by;

  s8v ac[6];
#pragma unroll
  for (int p = 0; p < 6; p++) ac[p] = *(const s8v*)&apkc[(p * 64 + l) * 8];

  // ---- phase 1: ccm t3 -> Ys (fp32 LDS) ----
#pragma unroll 1
  for (int tt = 0; tt < 8; tt++) {
    const int t = tt * 16 + tcol;
    f4v d = (f4v)0.f;
#pragma unroll
    for (int p = 0; p < 6; p++) {
      int dn = p * 2 + (q >> 1);
      int row = n + dn - 5;
      bool ok = (unsigned)row < (unsigned)N;
      int rowc = ok ? row : 0;
      const unsigned short* bp =
          &zin[(((size_t)by * N + rowc) * T + t) * 16 + (q & 1) * 8];
      s8v bfrag = *(const s8v*)bp;
      if (!ok) bfrag = (s8v){0, 0, 0, 0, 0, 0, 0, 0};
      d = __builtin_amdgcn_mfma_f32_16x16x32_bf16(ac[p], bfrag, d, 0, 0, 0);
    }
    const unsigned short* hp = resin + (((size_t)by * N + n) * T + t) * 16 + q * 4;
    u4s hb = *(const u4s*)hp;
#pragma unroll
    for (int r = 0; r < 4; r++)
      Ys[q * 4 + r][t] = fmaxf(bf2f(hb[r]) + fmaxf(d[r], 0.f), 0.f);
  }
  __syncthreads();

  // ---- phase 2: conv4 (full-T dot per output channel, wave reduce) ----
  const int t0 = l * 2;
  vf2 y[16];
#pragma unroll
  for (int ci = 0; ci < 16; ci++) y[ci] = *(const vf2*)&Ys[ci][t0];

#pragma unroll 1
  for (int o = 0; o < 16; o++) {
    vf2 s = (vf2)0.f;
#pragma unroll
    for (int ci = 0; ci < 16; ci++) {
      vf2 w = *(const vf2*)&w4[(size_t)(o * 16 + ci) * T + t0];
      s += w * y[ci];
    }
    float sum = s.x + s.y;
    sum += __shfl_down(sum, 32);
    sum += __shfl_down(sum, 16);
    sum += __shfl_down(sum, 8);
    sum += __shfl_down(sum, 4);
    sum += __shfl_down(sum, 2);
    sum += __shfl_down(sum, 1);
    if (l == 0) h4[((size_t)b * 16 + o) * N + n] = fmaxf(sum, 0.f);
  }
}

// ---------------------------------------------------------------------------
// K8: logits (torch reshape scramble) + softmax over N
// ---------------------------------------------------------------------------
__global__ __launch_bounds__(128) void final_kernel(
    const float* __restrict__ hl, const float* __restrict__ h4,
    const float* __restrict__ ow, const float* __restrict__ ob,
    float* __restrict__ out) {
  __shared__ float red[128];
  int b = blockIdx.x, n = threadIdx.x;
  bool valid = n < N;
  float lv = 0.f;
  if (valid) {
    int idx = b * N + n;
    int sb = idx & (B - 1);
    int sn = idx >> 8;
    const float* h = &hl[((size_t)sb * N + sn) * 16];
    float a = ob[0];
#pragma unroll
    for (int k = 0; k < 16; k++) a += h[k] * ow[k];
#pragma unroll
    for (int c = 0; c < 16; c++) a += h4[((size_t)b * 16 + c) * N + n] * ow[16 + c];
    lv = a;
  }
  red[n] = valid ? lv : -1e30f;
  __syncthreads();
  for (int off = 64; off > 0; off >>= 1) {
    if (n < off) red[n] = fmaxf(red[n], red[n + off]);
    __syncthreads();
  }
  float m = red[0];
  __syncthreads();
  float e = valid ? __expf(lv - m) : 0.f;
  red[n] = e;
  __syncthreads();
  for (int off = 64; off > 0; off >>= 1) {
    if (n < off) red[n] += red[n + off];
    __syncthreads();
  }
  float s = red[0];
  if (valid) out[(size_t)b * N + n] = e / s;
}

// ---------------------------------------------------------------------------
// Launch. Chunked over B. Buffers (all bf16 interleaved [Bc][N][T][C]):
// Zb1(8ch=4) + H1b(8ch=4) + Zb2a(16ch=8) + H2b(16ch=8) + Zb2b(16ch=8)
// = 32 NT-floats per b. Separate Zb2a/Zb2b avoid the cross-n WAR race
// inside the fused kernels. Y never hits global.
// ---------------------------------------------------------------------------
extern "C" void kernel_launch(void* const* d_in, const int* in_sizes, int n_in,
                              void* d_out, int out_size, void* d_ws, size_t ws_size,
                              hipStream_t stream) {
  const float* x    = (const float*)d_in[0];
  const float* pw   = (const float*)d_in[1];
  const float* pb   = (const float*)d_in[2];
  const float* w_ih = (const float*)d_in[3];
  const float* w_hh = (const float*)d_in[4];
  const float* b_ih = (const float*)d_in[5];
  const float* b_hh = (const float*)d_in[6];
  const float* t1d1 = (const float*)d_in[7];
  const float* t1d2 = (const float*)d_in[8];
  const float* t1c  = (const float*)d_in[9];
  const float* t1r  = (const float*)d_in[10];
  const float* t2d1 = (const float*)d_in[11];
  const float* t2d2 = (const float*)d_in[12];
  const float* t2c  = (const float*)d_in[13];
  const float* t2r  = (const float*)d_in[14];
  const float* t3d1 = (const float*)d_in[15];
  const float* t3d2 = (const float*)d_in[16];
  const float* t3c  = (const float*)d_in[17];
  const float* w4   = (const float*)d_in[18];
  const float* ow   = (const float*)d_in[19];
  const float* ob   = (const float*)d_in[20];
  float* outp = (float*)d_out;

  const size_t NT = (size_t)N * T;            // 12928
  const size_t Bn16 = (size_t)B * N * 16;
  const size_t unit = 32 * NT;                // floats per chunked b
  const size_t fixed = 2 * Bn16 + 8192;       // hl + h4 + apk

  int Bc = 4;
  const int cands[7] = {256, 128, 64, 32, 16, 8, 4};
  for (int i = 0; i < 7; i++) {
    if ((cands[i] * unit + fixed) * sizeof(float) <= ws_size) { Bc = cands[i]; break; }
  }

  float* ws = (float*)d_ws;
  float* hl = ws;                              // [B*N][16]
  float* h4 = hl + Bn16;                       // [B][16][N]
  unsigned short* apk = (unsigned short*)(h4 + Bn16);  // 22*512 ushorts
  float* p = h4 + Bn16 + 8192;
  unsigned short* Zb1  = (unsigned short*)p; p += (size_t)Bc * 4 * NT;
  unsigned short* H1b  = (unsigned short*)p; p += (size_t)Bc * 4 * NT;
  unsigned short* Zb2a = (unsigned short*)p; p += (size_t)Bc * 8 * NT;
  unsigned short* H2b  = (unsigned short*)p; p += (size_t)Bc * 8 * NT;
  unsigned short* Zb2b = (unsigned short*)p;

  prep_kernel<<<1, 64, 0, stream>>>(t1c, t2c, t3c, t2d1, t2d2, t3d1, t3d2, apk);
  lstm_kernel<<<(B * N) / 8, 64, 0, stream>>>(x, pw, pb, w_ih, w_hh, b_ih,
                                              b_hh, hl);

  dim3 g(N, Bc);
  for (int b0 = 0; b0 < B; b0 += Bc) {
    d12a_kernel<<<g, 128, 0, stream>>>(x, pw, pb, t1d1, t1d2, Zb1, b0);
    cd2_kernel<8, 2><<<g, 64, 0, stream>>>(
        Zb1, apk + 0 * 512, apk + 15 * 512, x, t1r, pw, pb, H1b, Zb2a, b0);
    cd2_kernel<16, 4><<<g, 64, 0, stream>>>(
        Zb2a, apk + 3 * 512, apk + 18 * 512, H1b, t2r, pw, pb, H2b, Zb2b, b0);
    cy_kernel<<<g, 64, 0, stream>>>(Zb2b, apk + 9 * 512, H2b, w4, h4, b0);
  }

  final_kernel<<<B, 128, 0, stream>>>(hl, h4, ow, ob, outp);
}